// Round 3
// baseline (843.689 us; speedup 1.0000x reference)
//
#include <hip/hip_runtime.h>

// ============================================================================
// XModel_66795331387584: complex phase-feature ridge loss on MI355X (gfx950)
//
// loss = mean_{a,z} sum_d | num_MN/den_MN - num_X/den_X |^2
// R2: denominators are tail-dominated (E[1/|den|^2] log-divergent) -> den path
// needs << bf16 precision. Fix: split-bf16 (hi+lo) GEMMs for den with fp32
// output; gamma_X leading term from fp32 K12; accurate sincosf. Numerators
// stay single-bf16 (relative error -> relative contribution error, safe).
//
// Buffers (ws, adaptive z-chunk ZC):
//  fixed: AphH[4]@0 (16MB) | AphL[4]@16M | Kbf@32M | K12T@40M | partials@48M
//  chunk@49M: Bt 20 planes [ZC][2048] bf16 (p0 gN_h,p1 gN_l,p2 gX_h,p3 gX_l,
//             p4-11 M_d*gMN^T, p12-19 X_d*gX^T) | den fp32 [4][1024][ZC] |
//             Cout bf16 [32][1024][ZC] (T1t fp32 [ZC][2048] overlays Cout)
// ============================================================================

typedef __bf16 bf16;
typedef __bf16 bf16x8 __attribute__((ext_vector_type(8)));
typedef float f32x4 __attribute__((ext_vector_type(4)));

#define AS1 __attribute__((address_space(1)))
#define AS3 __attribute__((address_space(3)))

__device__ __forceinline__ void async16(const void* g, void* l) {
  __builtin_amdgcn_global_load_lds((AS1 const unsigned int*)g,
                                   (AS3 unsigned int*)l, 16, 0, 0);
}

// ------------------------------- phases (hi/lo) -----------------------------
__global__ __launch_bounds__(256) void k_phases(
    const float* __restrict__ al, const float* __restrict__ Nm,
    const float* __restrict__ Xm, bf16* __restrict__ AphH,
    bf16* __restrict__ AphL) {
  const size_t PA = (size_t)1024 * 2048;
  int a = blockIdx.x;                      // 0..1023
  int j = blockIdx.y * 256 + threadIdx.x;  // 0..2047
  size_t o = (size_t)a * 2048 + j;
  float v[4] = {0.f, 0.f, 0.f, 0.f};
  if (a < 1000 && j < 2000) {
    const float4* N4 = (const float4*)Nm;
    const float4* X4 = (const float4*)Xm;
    const float4* A4 = (const float4*)al;
    float4 n0 = N4[j * 2], n1 = N4[j * 2 + 1];
    float4 x0 = X4[j * 2], x1 = X4[j * 2 + 1];
    float4 a0 = A4[a * 2], a1 = A4[a * 2 + 1];
    float pn = a0.x * n0.x + a0.y * n0.y + a0.z * n0.z + a0.w * n0.w +
               a1.x * n1.x + a1.y * n1.y + a1.z * n1.z + a1.w * n1.w;
    float px = a0.x * x0.x + a0.y * x0.y + a0.z * x0.z + a0.w * x0.w +
               a1.x * x1.x + a1.y * x1.y + a1.z * x1.z + a1.w * x1.w;
    sincosf(pn, &v[1], &v[0]);  // v0=cosN v1=sinN
    sincosf(px, &v[3], &v[2]);  // v2=cosX v3=sinX
  }
#pragma unroll
  for (int p = 0; p < 4; ++p) {
    bf16 h = (bf16)v[p];
    AphH[p * PA + o] = h;
    AphL[p * PA + o] = (bf16)(v[p] - (float)h);
  }
}

// --------------------------- converts --------------------------------------
__global__ __launch_bounds__(256) void k_cvt_straight(
    const float* __restrict__ K, bf16* __restrict__ Kb) {
  int e = (blockIdx.x * 256 + threadIdx.x) * 8;
  int j = e >> 11, k = e & 2047;
  bf16x8 v;
  if (j < 2000 && k < 2000) {
    const float4* s = (const float4*)(K + (size_t)j * 2000 + k);
    float4 f0 = s[0], f1 = s[1];
    v[0] = (bf16)f0.x; v[1] = (bf16)f0.y; v[2] = (bf16)f0.z; v[3] = (bf16)f0.w;
    v[4] = (bf16)f1.x; v[5] = (bf16)f1.y; v[6] = (bf16)f1.z; v[7] = (bf16)f1.w;
  } else {
    for (int i = 0; i < 8; ++i) v[i] = (bf16)0.f;
  }
  *(bf16x8*)(Kb + e) = v;
}

__global__ __launch_bounds__(256) void k_cvt_t(
    const float* __restrict__ src, bf16* __restrict__ dst) {
  int j0 = blockIdx.x * 64, z0 = blockIdx.y * 64;
  __shared__ float t[64][65];
  int tid = threadIdx.x;
  for (int e = tid; e < 4096; e += 256) {
    int r = e >> 6, c = e & 63;
    t[r][c] = (j0 + r < 2000 && z0 + c < 2000)
                  ? src[(size_t)(j0 + r) * 2000 + z0 + c] : 0.f;
  }
  __syncthreads();
  for (int e = tid; e < 4096; e += 256) {
    int r = e >> 6, c = e & 63;
    dst[(size_t)(z0 + r) * 2048 + j0 + c] = (bf16)t[c][r];
  }
}

// --------------------------- GEMM core (num / gemm1) ------------------------
// C[bm+..][bn+..] = sum_k A[m][k]*Bt[n][k]; A/B row stride 2048, K=2048.
template <int NA, typename CT>
__device__ __forceinline__ void mm_tile(
    const bf16* __restrict__ A0, const bf16* __restrict__ A1,
    const bf16* __restrict__ Bt, CT* __restrict__ C0, CT* __restrict__ C1,
    int bm, int bn, int ldc) {
  __shared__ __align__(16) bf16 lds[NA + 1][128][64];
  const int tid = threadIdx.x;
  const int w = tid >> 6, ln = tid & 63;
  const int r8 = ln >> 3, c8 = (ln & 7) * 8;

  f32x4 acc0[4][4], acc1[4][4];
#pragma unroll
  for (int i = 0; i < 4; i++)
#pragma unroll
    for (int j = 0; j < 4; j++) {
      acc0[i][j] = {0.f, 0.f, 0.f, 0.f};
      if (NA == 2) acc1[i][j] = {0.f, 0.f, 0.f, 0.f};
    }
  const int m0 = (w & 1) * 64, n0 = (w >> 1) * 64;
  const int fr = ln & 15, kq = (ln >> 4) * 8;

  for (int kt = 0; kt < 2048; kt += 64) {
#pragma unroll
    for (int q = 0; q < 4; ++q) {
      int row = (w * 4 + q) * 8 + r8;
      async16(A0 + (size_t)(bm + row) * 2048 + (kt + c8), &lds[0][row][c8]);
      if (NA == 2)
        async16(A1 + (size_t)(bm + row) * 2048 + (kt + c8), &lds[1][row][c8]);
      async16(Bt + (size_t)(bn + row) * 2048 + (kt + c8), &lds[NA][row][c8]);
    }
    __syncthreads();
#pragma unroll
    for (int ks = 0; ks < 64; ks += 32) {
      bf16x8 a0[4], a1[4], b[4];
#pragma unroll
      for (int i = 0; i < 4; i++) {
        a0[i] = *(const bf16x8*)&lds[0][m0 + i * 16 + fr][ks + kq];
        if (NA == 2) a1[i] = *(const bf16x8*)&lds[1][m0 + i * 16 + fr][ks + kq];
        b[i] = *(const bf16x8*)&lds[NA][n0 + i * 16 + fr][ks + kq];
      }
#pragma unroll
      for (int i = 0; i < 4; i++)
#pragma unroll
        for (int j = 0; j < 4; j++) {
          acc0[i][j] = __builtin_amdgcn_mfma_f32_16x16x32_bf16(
              a0[i], b[j], acc0[i][j], 0, 0, 0);
          if (NA == 2)
            acc1[i][j] = __builtin_amdgcn_mfma_f32_16x16x32_bf16(
                a1[i], b[j], acc1[i][j], 0, 0, 0);
        }
    }
    __syncthreads();
  }
  const int cr = (ln >> 4) * 4, cc = ln & 15;  // C/D: col=lane&15,row=quad*4+r
#pragma unroll
  for (int i = 0; i < 4; i++)
#pragma unroll
    for (int j = 0; j < 4; j++)
#pragma unroll
      for (int r = 0; r < 4; r++) {
        size_t idx =
            (size_t)(bm + m0 + i * 16 + cr + r) * ldc + (bn + n0 + j * 16 + cc);
        C0[idx] = (CT)acc0[i][j][r];
        if (NA == 2) C1[idx] = (CT)acc1[i][j][r];
      }
}

__global__ __launch_bounds__(256, 2) void gemm1_kernel(
    const bf16* __restrict__ K12T, const bf16* __restrict__ Kbf,
    float* __restrict__ T1t, int zg0) {
  // T1t[zl][j] = sum_k K12[k][zg0+zl]*K[j][k]  (fp32 out, local z rows)
  mm_tile<1, float>(K12T + (size_t)zg0 * 2048, nullptr, Kbf, T1t, nullptr,
                    blockIdx.y * 128, blockIdx.x * 128, 2048);
}

__global__ __launch_bounds__(256, 2) void gemm2_kernel(
    const bf16* __restrict__ AphH, const bf16* __restrict__ Bt,
    bf16* __restrict__ Cout, int ZC) {
  const size_t PA = (size_t)1024 * 2048;
  const size_t PL = (size_t)ZC * 2048;
  const size_t PC = (size_t)1024 * ZC;
  int bp = blockIdx.z;  // 0..15 num B-planes
  const bf16* Ac = AphH + (size_t)(bp < 8 ? 0 : 2) * PA;
  mm_tile<2, bf16>(Ac, Ac + PA, Bt + (size_t)(4 + bp) * PL,
                   Cout + (size_t)(2 * bp) * PC,
                   Cout + (size_t)(2 * bp + 1) * PC, blockIdx.x * 128,
                   blockIdx.y * 128, ZC);
}

// --------------------------- den GEMM (split-bf16, fp32 out) ----------------
__global__ __launch_bounds__(256, 2) void gemm_den_kernel(
    const bf16* __restrict__ AphH, const bf16* __restrict__ AphL,
    const bf16* __restrict__ Bt, float* __restrict__ den, int ZC) {
  const size_t PA = (size_t)1024 * 2048;
  const size_t PL = (size_t)ZC * 2048;
  const size_t PD = (size_t)1024 * ZC;
  int p = blockIdx.z;  // side*2+trig: 0 denN_re,1 denN_im,2 denX_re,3 denX_im
  int side = p >> 1, trig = p & 1;
  const bf16* Ah = AphH + (size_t)(side * 2 + trig) * PA;
  const bf16* Al = AphL + (size_t)(side * 2 + trig) * PA;
  const bf16* Bh = Bt + (size_t)(side * 2) * PL;
  const bf16* Bl = Bh + PL;
  float* C = den + (size_t)p * PD;
  int bm = blockIdx.x * 128, bn = blockIdx.y * 128;

  __shared__ __align__(16) bf16 lds[4][128][64];
  const int tid = threadIdx.x;
  const int w = tid >> 6, ln = tid & 63;
  const int r8 = ln >> 3, c8 = (ln & 7) * 8;

  f32x4 acc[4][4];
#pragma unroll
  for (int i = 0; i < 4; i++)
#pragma unroll
    for (int j = 0; j < 4; j++) acc[i][j] = {0.f, 0.f, 0.f, 0.f};
  const int m0 = (w & 1) * 64, n0 = (w >> 1) * 64;
  const int fr = ln & 15, kq = (ln >> 4) * 8;

  for (int kt = 0; kt < 2048; kt += 64) {
#pragma unroll
    for (int q = 0; q < 4; ++q) {
      int row = (w * 4 + q) * 8 + r8;
      async16(Ah + (size_t)(bm + row) * 2048 + (kt + c8), &lds[0][row][c8]);
      async16(Al + (size_t)(bm + row) * 2048 + (kt + c8), &lds[1][row][c8]);
      async16(Bh + (size_t)(bn + row) * 2048 + (kt + c8), &lds[2][row][c8]);
      async16(Bl + (size_t)(bn + row) * 2048 + (kt + c8), &lds[3][row][c8]);
    }
    __syncthreads();
#pragma unroll
    for (int ks = 0; ks < 64; ks += 32) {
      bf16x8 ah[4], alo[4], bh[4], blo[4];
#pragma unroll
      for (int i = 0; i < 4; i++) {
        ah[i]  = *(const bf16x8*)&lds[0][m0 + i * 16 + fr][ks + kq];
        alo[i] = *(const bf16x8*)&lds[1][m0 + i * 16 + fr][ks + kq];
        bh[i]  = *(const bf16x8*)&lds[2][n0 + i * 16 + fr][ks + kq];
        blo[i] = *(const bf16x8*)&lds[3][n0 + i * 16 + fr][ks + kq];
      }
#pragma unroll
      for (int i = 0; i < 4; i++)
#pragma unroll
        for (int j = 0; j < 4; j++) {
          acc[i][j] = __builtin_amdgcn_mfma_f32_16x16x32_bf16(
              alo[i], bh[j], acc[i][j], 0, 0, 0);
          acc[i][j] = __builtin_amdgcn_mfma_f32_16x16x32_bf16(
              ah[i], blo[j], acc[i][j], 0, 0, 0);
          acc[i][j] = __builtin_amdgcn_mfma_f32_16x16x32_bf16(
              ah[i], bh[j], acc[i][j], 0, 0, 0);
        }
    }
    __syncthreads();
  }
  const int cr = (ln >> 4) * 4, cc = ln & 15;
#pragma unroll
  for (int i = 0; i < 4; i++)
#pragma unroll
    for (int j = 0; j < 4; j++)
#pragma unroll
      for (int r = 0; r < 4; r++) {
        size_t idx =
            (size_t)(bm + m0 + i * 16 + cr + r) * ZC + (bn + n0 + j * 16 + cc);
        C[idx] = acc[i][j][r];
      }
}

// --------------------------- build gamma_X planes ---------------------------
__global__ __launch_bounds__(256) void k_buildGX(
    const float* __restrict__ K12, const float* __restrict__ T1t,
    const float* __restrict__ Xm, const float* __restrict__ ll,
    bf16* __restrict__ Bt, int zg0, int ZC) {
  const size_t PL = (size_t)ZC * 2048;
  int j0 = blockIdx.x * 64, zl0 = blockIdx.y * 64;
  int tid = threadIdx.x;
  float inv = 1.f / (2000.f * __expf(ll[0]));
  __shared__ float t[64][65];
  for (int e = tid; e < 4096; e += 256) {
    int r = e >> 6, c = e & 63;  // r=j row, c=z col
    t[r][c] = (j0 + r < 2000 && zg0 + zl0 + c < 2000)
                  ? K12[(size_t)(j0 + r) * 2000 + zg0 + zl0 + c] : 0.f;
  }
  __syncthreads();
  for (int e = tid; e < 4096; e += 256) {
    int r = e >> 6, c = e & 63;  // r=local z row, c=j col
    int jj = j0 + c, zl = zl0 + r;
    float t1 = T1t[(size_t)zl * 2048 + jj];
    float gx = (t[c][r] - t1 * inv) * inv;  // fp32 gamma_X^T[z][j]
    size_t ob = (size_t)zl * 2048 + jj;
    bf16 h = (bf16)gx;
    Bt[2 * PL + ob] = h;
    Bt[3 * PL + ob] = (bf16)(gx - (float)h);
#pragma unroll
    for (int d = 0; d < 8; ++d) {
      float xv = (jj < 2000) ? Xm[jj * 8 + d] : 0.f;
      Bt[(size_t)(12 + d) * PL + ob] = (bf16)(gx * xv);
    }
  }
}

// --------------------------- build gN / gMN planes --------------------------
__global__ __launch_bounds__(256) void k_buildB(
    const float* __restrict__ gN, const float* __restrict__ gMN,
    const float* __restrict__ Mm, bf16* __restrict__ Bt, int zg0, int ZC) {
  const size_t PL = (size_t)ZC * 2048;
  int j0 = blockIdx.x * 64, zl0 = blockIdx.y * 64;
  int tid = threadIdx.x;
  __shared__ float t[64][65];

  // p0/p1: gammaN^T hi/lo
  for (int e = tid; e < 4096; e += 256) {
    int r = e >> 6, c = e & 63;
    t[r][c] = (j0 + r < 2000 && zg0 + zl0 + c < 2000)
                  ? gN[(size_t)(j0 + r) * 2000 + zg0 + zl0 + c] : 0.f;
  }
  __syncthreads();
  for (int e = tid; e < 4096; e += 256) {
    int r = e >> 6, c = e & 63;
    float g = t[c][r];
    size_t ob = (size_t)(zl0 + r) * 2048 + (j0 + c);
    bf16 h = (bf16)g;
    Bt[0 * PL + ob] = h;
    Bt[1 * PL + ob] = (bf16)(g - (float)h);
  }
  __syncthreads();

  // p4..11: M_d * gammaMN^T (single bf16)
  for (int e = tid; e < 4096; e += 256) {
    int r = e >> 6, c = e & 63;
    t[r][c] = (j0 + r < 2000 && zg0 + zl0 + c < 2000)
                  ? gMN[(size_t)(j0 + r) * 2000 + zg0 + zl0 + c] : 0.f;
  }
  __syncthreads();
  for (int e = tid; e < 4096; e += 256) {
    int r = e >> 6, c = e & 63;
    int jj = j0 + c;
    float g = t[c][r];
    size_t ob = (size_t)(zl0 + r) * 2048 + jj;
#pragma unroll
    for (int d = 0; d < 8; ++d) {
      float mv = (jj < 2000) ? Mm[jj * 8 + d] : 0.f;
      Bt[(size_t)(4 + d) * PL + ob] = (bf16)(g * mv);
    }
  }
}

// --------------------------- final reduction -------------------------------
__device__ __forceinline__ void load8f(const bf16* p, float* o) {
  uint4 u = *(const uint4*)p;
  o[0] = __uint_as_float(u.x << 16);
  o[1] = __uint_as_float(u.x & 0xffff0000u);
  o[2] = __uint_as_float(u.y << 16);
  o[3] = __uint_as_float(u.y & 0xffff0000u);
  o[4] = __uint_as_float(u.z << 16);
  o[5] = __uint_as_float(u.z & 0xffff0000u);
  o[6] = __uint_as_float(u.w << 16);
  o[7] = __uint_as_float(u.w & 0xffff0000u);
}
__device__ __forceinline__ void load8d(const float* p, float* o) {
  float4 f0 = ((const float4*)p)[0], f1 = ((const float4*)p)[1];
  o[0] = f0.x; o[1] = f0.y; o[2] = f0.z; o[3] = f0.w;
  o[4] = f1.x; o[5] = f1.y; o[6] = f1.z; o[7] = f1.w;
}

__global__ __launch_bounds__(256) void k_reduce(
    const bf16* __restrict__ C, const float* __restrict__ den,
    float* __restrict__ partials, int ZC, int zg0, int slot) {
  const size_t PS = (size_t)1024 * ZC;
  int a = blockIdx.x, tid = threadIdx.x;
  float acc = 0.f;
  for (int z = tid * 8; z < ZC; z += 2048) {
    if (zg0 + z >= 2000) break;
    size_t base = (size_t)a * ZC + z;
    float mdr[8], mdi[8], xdr[8], xdi[8], im[8], ix[8];
    load8d(den + 0 * PS + base, mdr);
    load8d(den + 1 * PS + base, mdi);
    load8d(den + 2 * PS + base, xdr);
    load8d(den + 3 * PS + base, xdi);
#pragma unroll
    for (int e = 0; e < 8; ++e) {
      im[e] = 1.f / (mdr[e] * mdr[e] + mdi[e] * mdi[e]);
      ix[e] = 1.f / (xdr[e] * xdr[e] + xdi[e] * xdi[e]);
    }
#pragma unroll
    for (int d = 0; d < 8; ++d) {
      float ar[8], ai[8], br[8], bi[8];
      load8f(C + (size_t)(2 * d) * PS + base, ar);
      load8f(C + (size_t)(2 * d + 1) * PS + base, ai);
      load8f(C + (size_t)(16 + 2 * d) * PS + base, br);
      load8f(C + (size_t)(17 + 2 * d) * PS + base, bi);
#pragma unroll
      for (int e = 0; e < 8; ++e) {
        float r1 = (ar[e] * mdr[e] + ai[e] * mdi[e]) * im[e];
        float i1 = (ai[e] * mdr[e] - ar[e] * mdi[e]) * im[e];
        float r2 = (br[e] * xdr[e] + bi[e] * xdi[e]) * ix[e];
        float i2 = (bi[e] * xdr[e] - br[e] * xdi[e]) * ix[e];
        float dr = r1 - r2, di = i1 - i2;
        acc += dr * dr + di * di;
      }
    }
  }
  for (int off = 32; off; off >>= 1) acc += __shfl_down(acc, off, 64);
  __shared__ float red[4];
  if (!(tid & 63)) red[tid >> 6] = acc;
  __syncthreads();
  if (!tid) partials[slot * 1000 + a] = red[0] + red[1] + red[2] + red[3];
}

__global__ __launch_bounds__(256) void k_final(const float* __restrict__ partials,
                                               float* __restrict__ out, int n) {
  int tid = threadIdx.x;
  float s = 0.f;
  for (int i = tid; i < n; i += 256) s += partials[i];
  for (int off = 32; off; off >>= 1) s += __shfl_down(s, off, 64);
  __shared__ float red[4];
  if (!(tid & 63)) red[tid >> 6] = s;
  __syncthreads();
  if (!tid) out[0] = (red[0] + red[1] + red[2] + red[3]) * (1.f / 2000000.f);
}

// ============================================================================
extern "C" void kernel_launch(void* const* d_in, const int* in_sizes, int n_in,
                              void* d_out, int out_size, void* d_ws,
                              size_t ws_size, hipStream_t stream) {
  const float* Mm  = (const float*)d_in[0];
  const float* Nm  = (const float*)d_in[1];
  const float* Xm  = (const float*)d_in[2];
  const float* ll  = (const float*)d_in[3];
  const float* K11 = (const float*)d_in[4];
  const float* K12 = (const float*)d_in[5];
  const float* gMN = (const float*)d_in[6];
  const float* gN  = (const float*)d_in[7];
  const float* al  = (const float*)d_in[8];

  char* ws = (char*)d_ws;
  const size_t MB = 1024 * 1024;
  bf16* AphH     = (bf16*)(ws);             // 16 MB
  bf16* AphL     = (bf16*)(ws + 16 * MB);   // 16 MB
  bf16* Kbf      = (bf16*)(ws + 32 * MB);   // 8 MB
  bf16* K12T     = (bf16*)(ws + 40 * MB);   // 8 MB
  float* partials= (float*)(ws + 48 * MB);  // <=64 KB
  char* chunkRgn = ws + 49 * MB;

  // chunk: Bt 81920*ZC | den 16384*ZC | Cout 65536*ZC (T1t overlays Cout)
  size_t avail = (ws_size > 49 * MB) ? ws_size - 49 * MB : 0;
  int ZC = 2048;
  while (ZC > 128 && (size_t)163840 * ZC > avail) ZC >>= 1;
  int NC = 2048 / ZC;
  bf16* Btc   = (bf16*)(chunkRgn);
  float* denc = (float*)(chunkRgn + (size_t)81920 * ZC);
  bf16* Coutc = (bf16*)(chunkRgn + (size_t)98304 * ZC);
  float* T1tc = (float*)Coutc;  // fp32 [ZC][2048], dead before Cout written

  k_phases<<<dim3(1024, 8), dim3(256), 0, stream>>>(al, Nm, Xm, AphH, AphL);
  k_cvt_straight<<<dim3(2048), dim3(256), 0, stream>>>(K11, Kbf);
  k_cvt_t<<<dim3(32, 32), dim3(256), 0, stream>>>(K12, K12T);
  for (int c = 0; c < NC; ++c) {
    int zg0 = c * ZC;
    gemm1_kernel<<<dim3(16, ZC / 128), dim3(256), 0, stream>>>(K12T, Kbf, T1tc,
                                                               zg0);
    k_buildGX<<<dim3(32, ZC / 64), dim3(256), 0, stream>>>(K12, T1tc, Xm, ll,
                                                           Btc, zg0, ZC);
    k_buildB<<<dim3(32, ZC / 64), dim3(256), 0, stream>>>(gN, gMN, Mm, Btc,
                                                          zg0, ZC);
    gemm2_kernel<<<dim3(8, ZC / 128, 16), dim3(256), 0, stream>>>(AphH, Btc,
                                                                  Coutc, ZC);
    gemm_den_kernel<<<dim3(8, ZC / 128, 4), dim3(256), 0, stream>>>(
        AphH, AphL, Btc, denc, ZC);
    k_reduce<<<dim3(1000), dim3(256), 0, stream>>>(Coutc, denc, partials, ZC,
                                                   zg0, c);
  }
  k_final<<<dim3(1), dim3(256), 0, stream>>>(partials, (float*)d_out,
                                             NC * 1000);
  (void)in_sizes; (void)n_in; (void)out_size;
}

// Round 4
// 699.786 us; speedup vs baseline: 1.2056x; 1.2056x over previous
//
#include <hip/hip_runtime.h>

// ============================================================================
// XModel_66795331387584: complex phase-feature ridge loss on MI355X (gfx950)
//
// loss = mean_{a,z} sum_d | num_MN/den_MN - num_X/den_X |^2
// den path: split-bf16 (hi+lo) GEMMs, fp32 out (tail-dominated 1/|den|^2).
// gamma_X via 1-term Neumann: gx = (K12 - K@K12/reg)/reg, fused into gemm1
// epilogue (reads fp32 K12 directly; correction term bf16 is 4e-6 rel).
//
// R3 structure: k_phases, cvt x2, then per z-chunk (ZC adaptive):
//   k_prep   : branch A = gemm1(K12T@Kbf) + gx epilogue -> Bt planes 2,3,12-19
//              branch B = buildB (gN hi/lo, M_d*gMN)    -> Bt planes 0,1,4-11
//   gemm2    : 16 num planes, 2 C-planes/block (cos/sin share B)
//   k_den    : 4 den planes, split-bf16 3-MFMA chain, 128x64 tiles (512 blk)
//   k_reduce : ratios + |diff|^2 partial sums (2 a-rows/block)
// ============================================================================

typedef __bf16 bf16;
typedef __bf16 bf16x8 __attribute__((ext_vector_type(8)));
typedef float f32x4 __attribute__((ext_vector_type(4)));

#define AS1 __attribute__((address_space(1)))
#define AS3 __attribute__((address_space(3)))

__device__ __forceinline__ void async16(const void* g, void* l) {
  __builtin_amdgcn_global_load_lds((AS1 const unsigned int*)g,
                                   (AS3 unsigned int*)l, 16, 0, 0);
}

// ------------------------------- phases (hi/lo) -----------------------------
__global__ __launch_bounds__(256) void k_phases(
    const float* __restrict__ al, const float* __restrict__ Nm,
    const float* __restrict__ Xm, bf16* __restrict__ AphH,
    bf16* __restrict__ AphL) {
  const size_t PA = (size_t)1024 * 2048;
  int a = blockIdx.x;                      // 0..1023
  int j = blockIdx.y * 256 + threadIdx.x;  // 0..2047
  size_t o = (size_t)a * 2048 + j;
  float v[4] = {0.f, 0.f, 0.f, 0.f};
  if (a < 1000 && j < 2000) {
    const float4* N4 = (const float4*)Nm;
    const float4* X4 = (const float4*)Xm;
    const float4* A4 = (const float4*)al;
    float4 n0 = N4[j * 2], n1 = N4[j * 2 + 1];
    float4 x0 = X4[j * 2], x1 = X4[j * 2 + 1];
    float4 a0 = A4[a * 2], a1 = A4[a * 2 + 1];
    float pn = a0.x * n0.x + a0.y * n0.y + a0.z * n0.z + a0.w * n0.w +
               a1.x * n1.x + a1.y * n1.y + a1.z * n1.z + a1.w * n1.w;
    float px = a0.x * x0.x + a0.y * x0.y + a0.z * x0.z + a0.w * x0.w +
               a1.x * x1.x + a1.y * x1.y + a1.z * x1.z + a1.w * x1.w;
    sincosf(pn, &v[1], &v[0]);
    sincosf(px, &v[3], &v[2]);
  }
#pragma unroll
  for (int p = 0; p < 4; ++p) {
    bf16 h = (bf16)v[p];
    AphH[p * PA + o] = h;
    AphL[p * PA + o] = (bf16)(v[p] - (float)h);
  }
}

// --------------------------- converts --------------------------------------
__global__ __launch_bounds__(256) void k_cvt_straight(
    const float* __restrict__ K, bf16* __restrict__ Kb) {
  int e = (blockIdx.x * 256 + threadIdx.x) * 8;
  int j = e >> 11, k = e & 2047;
  bf16x8 v;
  if (j < 2000 && k < 2000) {
    const float4* s = (const float4*)(K + (size_t)j * 2000 + k);
    float4 f0 = s[0], f1 = s[1];
    v[0] = (bf16)f0.x; v[1] = (bf16)f0.y; v[2] = (bf16)f0.z; v[3] = (bf16)f0.w;
    v[4] = (bf16)f1.x; v[5] = (bf16)f1.y; v[6] = (bf16)f1.z; v[7] = (bf16)f1.w;
  } else {
    for (int i = 0; i < 8; ++i) v[i] = (bf16)0.f;
  }
  *(bf16x8*)(Kb + e) = v;
}

__global__ __launch_bounds__(256) void k_cvt_t(
    const float* __restrict__ src, bf16* __restrict__ dst) {
  int j0 = blockIdx.x * 64, z0 = blockIdx.y * 64;
  __shared__ float t[64][65];
  int tid = threadIdx.x;
  for (int e = tid; e < 4096; e += 256) {
    int r = e >> 6, c = e & 63;
    t[r][c] = (j0 + r < 2000 && z0 + c < 2000)
                  ? src[(size_t)(j0 + r) * 2000 + z0 + c] : 0.f;
  }
  __syncthreads();
  for (int e = tid; e < 4096; e += 256) {
    int r = e >> 6, c = e & 63;
    dst[(size_t)(z0 + r) * 2048 + j0 + c] = (bf16)t[c][r];
  }
}

// --------------------------- GEMM core (num planes) -------------------------
// C[bm+..][bn+..] = sum_k A[m][k]*Bt[n][k]; A/B row stride 2048, K=2048.
template <int NA, typename CT>
__device__ __forceinline__ void mm_tile(
    const bf16* __restrict__ A0, const bf16* __restrict__ A1,
    const bf16* __restrict__ Bt, CT* __restrict__ C0, CT* __restrict__ C1,
    int bm, int bn, int ldc) {
  __shared__ __align__(16) bf16 lds[NA + 1][128][64];
  const int tid = threadIdx.x;
  const int w = tid >> 6, ln = tid & 63;
  const int r8 = ln >> 3, c8 = (ln & 7) * 8;

  f32x4 acc0[4][4], acc1[4][4];
#pragma unroll
  for (int i = 0; i < 4; i++)
#pragma unroll
    for (int j = 0; j < 4; j++) {
      acc0[i][j] = {0.f, 0.f, 0.f, 0.f};
      if (NA == 2) acc1[i][j] = {0.f, 0.f, 0.f, 0.f};
    }
  const int m0 = (w & 1) * 64, n0 = (w >> 1) * 64;
  const int fr = ln & 15, kq = (ln >> 4) * 8;

  for (int kt = 0; kt < 2048; kt += 64) {
#pragma unroll
    for (int q = 0; q < 4; ++q) {
      int row = (w * 4 + q) * 8 + r8;
      async16(A0 + (size_t)(bm + row) * 2048 + (kt + c8), &lds[0][row][c8]);
      if (NA == 2)
        async16(A1 + (size_t)(bm + row) * 2048 + (kt + c8), &lds[1][row][c8]);
      async16(Bt + (size_t)(bn + row) * 2048 + (kt + c8), &lds[NA][row][c8]);
    }
    __syncthreads();
#pragma unroll
    for (int ks = 0; ks < 64; ks += 32) {
      bf16x8 a0[4], a1[4], b[4];
#pragma unroll
      for (int i = 0; i < 4; i++) {
        a0[i] = *(const bf16x8*)&lds[0][m0 + i * 16 + fr][ks + kq];
        if (NA == 2) a1[i] = *(const bf16x8*)&lds[1][m0 + i * 16 + fr][ks + kq];
        b[i] = *(const bf16x8*)&lds[NA][n0 + i * 16 + fr][ks + kq];
      }
#pragma unroll
      for (int i = 0; i < 4; i++)
#pragma unroll
        for (int j = 0; j < 4; j++) {
          acc0[i][j] = __builtin_amdgcn_mfma_f32_16x16x32_bf16(
              a0[i], b[j], acc0[i][j], 0, 0, 0);
          if (NA == 2)
            acc1[i][j] = __builtin_amdgcn_mfma_f32_16x16x32_bf16(
                a1[i], b[j], acc1[i][j], 0, 0, 0);
        }
    }
    __syncthreads();
  }
  const int cr = (ln >> 4) * 4, cc = ln & 15;  // C/D: col=lane&15,row=quad*4+r
#pragma unroll
  for (int i = 0; i < 4; i++)
#pragma unroll
    for (int j = 0; j < 4; j++)
#pragma unroll
      for (int r = 0; r < 4; r++) {
        size_t idx =
            (size_t)(bm + m0 + i * 16 + cr + r) * ldc + (bn + n0 + j * 16 + cc);
        C0[idx] = (CT)acc0[i][j][r];
        if (NA == 2) C1[idx] = (CT)acc1[i][j][r];
      }
}

__global__ __launch_bounds__(256, 2) void gemm2_kernel(
    const bf16* __restrict__ AphH, const bf16* __restrict__ Bt,
    bf16* __restrict__ Cout, int ZC) {
  const size_t PA = (size_t)1024 * 2048;
  const size_t PL = (size_t)ZC * 2048;
  const size_t PC = (size_t)1024 * ZC;
  int bp = blockIdx.z;  // 0..15
  const bf16* Ac = AphH + (size_t)(bp < 8 ? 0 : 2) * PA;
  mm_tile<2, bf16>(Ac, Ac + PA, Bt + (size_t)(4 + bp) * PL,
                   Cout + (size_t)(2 * bp) * PC,
                   Cout + (size_t)(2 * bp + 1) * PC, blockIdx.x * 128,
                   blockIdx.y * 128, ZC);
}

// ------------- k_prep: gemm1+gammaX epilogue (A) + buildB (B) ---------------
__global__ __launch_bounds__(256, 2) void k_prep(
    const bf16* __restrict__ K12T, const bf16* __restrict__ Kbf,
    const float* __restrict__ K12, const float* __restrict__ Xm,
    const float* __restrict__ ll, const float* __restrict__ gN,
    const float* __restrict__ gMN, const float* __restrict__ Mm,
    bf16* __restrict__ Bt, int zg0, int ZC, int NB1) {
  const size_t PL = (size_t)ZC * 2048;
  __shared__ __align__(16) char smem[32768];
  const int tid = threadIdx.x;

  if ((int)blockIdx.x < NB1) {
    // ---- branch A: T1[z][j] = sum_k K12T[zg0+z][k]*Kbf[j][k]; gx epilogue
    bf16(*lds)[128][64] = (bf16(*)[128][64])smem;  // [2][128][64]
    int bm = ((int)blockIdx.x >> 4) * 128;  // z-tile (chunk-local)
    int bn = ((int)blockIdx.x & 15) * 128;  // j-tile
    const bf16* A0 = K12T + (size_t)zg0 * 2048;
    const int w = tid >> 6, ln = tid & 63;
    const int r8 = ln >> 3, c8 = (ln & 7) * 8;
    f32x4 acc[4][4];
#pragma unroll
    for (int i = 0; i < 4; i++)
#pragma unroll
      for (int j = 0; j < 4; j++) acc[i][j] = {0.f, 0.f, 0.f, 0.f};
    const int m0 = (w & 1) * 64, n0 = (w >> 1) * 64;
    const int fr = ln & 15, kq = (ln >> 4) * 8;
    for (int kt = 0; kt < 2048; kt += 64) {
#pragma unroll
      for (int q = 0; q < 4; ++q) {
        int row = (w * 4 + q) * 8 + r8;
        async16(A0 + (size_t)(bm + row) * 2048 + (kt + c8), &lds[0][row][c8]);
        async16(Kbf + (size_t)(bn + row) * 2048 + (kt + c8), &lds[1][row][c8]);
      }
      __syncthreads();
#pragma unroll
      for (int ks = 0; ks < 64; ks += 32) {
        bf16x8 a[4], b[4];
#pragma unroll
        for (int i = 0; i < 4; i++) {
          a[i] = *(const bf16x8*)&lds[0][m0 + i * 16 + fr][ks + kq];
          b[i] = *(const bf16x8*)&lds[1][n0 + i * 16 + fr][ks + kq];
        }
#pragma unroll
        for (int i = 0; i < 4; i++)
#pragma unroll
          for (int j = 0; j < 4; j++)
            acc[i][j] = __builtin_amdgcn_mfma_f32_16x16x32_bf16(
                a[i], b[j], acc[i][j], 0, 0, 0);
      }
      __syncthreads();
    }
    float inv = 1.f / (2000.f * __expf(ll[0]));
    const int cr = (ln >> 4) * 4, cc = ln & 15;
    const float4* X4 = (const float4*)Xm;
#pragma unroll
    for (int i = 0; i < 4; i++)
#pragma unroll
      for (int j = 0; j < 4; j++) {
        int zl = bm + m0 + i * 16 + cr;
        int jj = bn + n0 + j * 16 + cc;
        float xv[8];
        bool jok = jj < 2000;
        if (jok) {
          float4 xa = X4[jj * 2], xb = X4[jj * 2 + 1];
          xv[0] = xa.x; xv[1] = xa.y; xv[2] = xa.z; xv[3] = xa.w;
          xv[4] = xb.x; xv[5] = xb.y; xv[6] = xb.z; xv[7] = xb.w;
        } else {
#pragma unroll
          for (int d = 0; d < 8; ++d) xv[d] = 0.f;
        }
#pragma unroll
        for (int r = 0; r < 4; r++) {
          int z = zl + r, zg = zg0 + z;
          float k12 = (jok && zg < 2000) ? K12[(size_t)jj * 2000 + zg] : 0.f;
          float gx = jok ? (k12 - acc[i][j][r] * inv) * inv : 0.f;
          size_t ob = (size_t)z * 2048 + jj;
          bf16 h = (bf16)gx;
          Bt[2 * PL + ob] = h;
          Bt[3 * PL + ob] = (bf16)(gx - (float)h);
#pragma unroll
          for (int d = 0; d < 8; ++d)
            Bt[(size_t)(12 + d) * PL + ob] = (bf16)(gx * xv[d]);
        }
      }
  } else {
    // ---- branch B: gN hi/lo (planes 0,1), M_d*gMN (planes 4..11)
    float(*t)[65] = (float(*)[65])smem;  // 64x65
    int bid = (int)blockIdx.x - NB1;
    int j0 = (bid & 31) * 64;
    int zl0 = (bid >> 5) * 64;
    int zg = zg0 + zl0;

    for (int e = tid; e < 4096; e += 256) {
      int r = e >> 6, c = e & 63;  // r=j row, c=z col
      t[r][c] = (j0 + r < 2000 && zg + c < 2000)
                    ? gN[(size_t)(j0 + r) * 2000 + zg + c] : 0.f;
    }
    __syncthreads();
#pragma unroll
    for (int it = 0; it < 2; ++it) {
      int idx = it * 256 + tid;
      int zr = idx >> 3, c8 = (idx & 7) * 8;
      bf16x8 vh, vl;
#pragma unroll
      for (int e = 0; e < 8; ++e) {
        float g = t[c8 + e][zr];
        bf16 h = (bf16)g;
        vh[e] = h;
        vl[e] = (bf16)(g - (float)h);
      }
      size_t ob = (size_t)(zl0 + zr) * 2048 + j0 + c8;
      *(bf16x8*)(Bt + 0 * PL + ob) = vh;
      *(bf16x8*)(Bt + 1 * PL + ob) = vl;
    }
    __syncthreads();

    for (int e = tid; e < 4096; e += 256) {
      int r = e >> 6, c = e & 63;
      t[r][c] = (j0 + r < 2000 && zg + c < 2000)
                    ? gMN[(size_t)(j0 + r) * 2000 + zg + c] : 0.f;
    }
    __syncthreads();
    const float4* M4 = (const float4*)Mm;
#pragma unroll
    for (int it = 0; it < 2; ++it) {
      int idx = it * 256 + tid;
      int zr = idx >> 3, c8 = (idx & 7) * 8;
      float g[8], mrow[8][8];
#pragma unroll
      for (int e = 0; e < 8; ++e) {
        g[e] = t[c8 + e][zr];
        int jj = j0 + c8 + e;
        if (jj < 2000) {
          float4 ma = M4[jj * 2], mb = M4[jj * 2 + 1];
          mrow[e][0] = ma.x; mrow[e][1] = ma.y; mrow[e][2] = ma.z;
          mrow[e][3] = ma.w; mrow[e][4] = mb.x; mrow[e][5] = mb.y;
          mrow[e][6] = mb.z; mrow[e][7] = mb.w;
        } else {
#pragma unroll
          for (int d = 0; d < 8; ++d) mrow[e][d] = 0.f;
        }
      }
      size_t ob = (size_t)(zl0 + zr) * 2048 + j0 + c8;
#pragma unroll
      for (int d = 0; d < 8; ++d) {
        bf16x8 v;
#pragma unroll
        for (int e = 0; e < 8; ++e) v[e] = (bf16)(g[e] * mrow[e][d]);
        *(bf16x8*)(Bt + (size_t)(4 + d) * PL + ob) = v;
      }
    }
  }
}

// --------------------------- den GEMM (split-bf16, 128x64 tiles) ------------
__global__ __launch_bounds__(256, 2) void k_den(
    const bf16* __restrict__ AphH, const bf16* __restrict__ AphL,
    const bf16* __restrict__ Bt, float* __restrict__ den, int ZC) {
  const size_t PA = (size_t)1024 * 2048;
  const size_t PL = (size_t)ZC * 2048;
  const size_t PD = (size_t)1024 * ZC;
  int p = blockIdx.z;  // 0 denN_re,1 denN_im,2 denX_re,3 denX_im
  int side = p >> 1, trig = p & 1;
  const bf16* Ah = AphH + (size_t)(side * 2 + trig) * PA;
  const bf16* Al = AphL + (size_t)(side * 2 + trig) * PA;
  const bf16* Bh = Bt + (size_t)(side * 2) * PL;
  const bf16* Bl = Bh + PL;
  float* C = den + (size_t)p * PD;
  int bm = blockIdx.x * 128, bn = blockIdx.y * 64;

  // LDS rows: [0,128)=Ah [128,256)=Al [256,320)=Bh [320,384)=Bl
  __shared__ __align__(16) bf16 lds[384][64];
  const int tid = threadIdx.x;
  const int w = tid >> 6, ln = tid & 63;
  const int r32 = tid >> 3, c8 = (tid & 7) * 8;

  f32x4 acc[4][2];
#pragma unroll
  for (int i = 0; i < 4; i++)
#pragma unroll
    for (int j = 0; j < 2; j++) acc[i][j] = {0.f, 0.f, 0.f, 0.f};
  const int m0 = (w & 1) * 64, n0 = (w >> 1) * 32;
  const int fr = ln & 15, kq = (ln >> 4) * 8;

  for (int kt = 0; kt < 2048; kt += 64) {
#pragma unroll
    for (int q = 0; q < 4; ++q) {
      int row = q * 32 + r32;
      async16(Ah + (size_t)(bm + row) * 2048 + (kt + c8), &lds[row][c8]);
      async16(Al + (size_t)(bm + row) * 2048 + (kt + c8), &lds[128 + row][c8]);
    }
#pragma unroll
    for (int q = 0; q < 2; ++q) {
      int row = q * 32 + r32;
      async16(Bh + (size_t)(bn + row) * 2048 + (kt + c8), &lds[256 + row][c8]);
      async16(Bl + (size_t)(bn + row) * 2048 + (kt + c8), &lds[320 + row][c8]);
    }
    __syncthreads();
#pragma unroll
    for (int ks = 0; ks < 64; ks += 32) {
      bf16x8 ah[4], alo[4], bh[2], blo[2];
#pragma unroll
      for (int i = 0; i < 4; i++) {
        ah[i]  = *(const bf16x8*)&lds[m0 + i * 16 + fr][ks + kq];
        alo[i] = *(const bf16x8*)&lds[128 + m0 + i * 16 + fr][ks + kq];
      }
#pragma unroll
      for (int j = 0; j < 2; j++) {
        bh[j]  = *(const bf16x8*)&lds[256 + n0 + j * 16 + fr][ks + kq];
        blo[j] = *(const bf16x8*)&lds[320 + n0 + j * 16 + fr][ks + kq];
      }
#pragma unroll
      for (int i = 0; i < 4; i++)
#pragma unroll
        for (int j = 0; j < 2; j++) {
          acc[i][j] = __builtin_amdgcn_mfma_f32_16x16x32_bf16(
              alo[i], bh[j], acc[i][j], 0, 0, 0);
          acc[i][j] = __builtin_amdgcn_mfma_f32_16x16x32_bf16(
              ah[i], blo[j], acc[i][j], 0, 0, 0);
          acc[i][j] = __builtin_amdgcn_mfma_f32_16x16x32_bf16(
              ah[i], bh[j], acc[i][j], 0, 0, 0);
        }
    }
    __syncthreads();
  }
  const int cr = (ln >> 4) * 4, cc = ln & 15;
#pragma unroll
  for (int i = 0; i < 4; i++)
#pragma unroll
    for (int j = 0; j < 2; j++)
#pragma unroll
      for (int r = 0; r < 4; r++) {
        size_t idx =
            (size_t)(bm + m0 + i * 16 + cr + r) * ZC + (bn + n0 + j * 16 + cc);
        C[idx] = acc[i][j][r];
      }
}

// --------------------------- final reduction -------------------------------
__device__ __forceinline__ void load8f(const bf16* p, float* o) {
  uint4 u = *(const uint4*)p;
  o[0] = __uint_as_float(u.x << 16);
  o[1] = __uint_as_float(u.x & 0xffff0000u);
  o[2] = __uint_as_float(u.y << 16);
  o[3] = __uint_as_float(u.y & 0xffff0000u);
  o[4] = __uint_as_float(u.z << 16);
  o[5] = __uint_as_float(u.z & 0xffff0000u);
  o[6] = __uint_as_float(u.w << 16);
  o[7] = __uint_as_float(u.w & 0xffff0000u);
}
__device__ __forceinline__ void load8d(const float* p, float* o) {
  float4 f0 = ((const float4*)p)[0], f1 = ((const float4*)p)[1];
  o[0] = f0.x; o[1] = f0.y; o[2] = f0.z; o[3] = f0.w;
  o[4] = f1.x; o[5] = f1.y; o[6] = f1.z; o[7] = f1.w;
}

__global__ __launch_bounds__(256) void k_reduce(
    const bf16* __restrict__ C, const float* __restrict__ den,
    float* __restrict__ partials, int ZC, int zg0, int slot) {
  const size_t PS = (size_t)1024 * ZC;
  int tid = threadIdx.x;
  int a = blockIdx.x * 2 + (tid >> 7);  // 2 a-rows per block
  int zt = tid & 127;
  float acc = 0.f;
  for (int z = zt * 8; z < ZC; z += 1024) {
    if (zg0 + z >= 2000) break;
    size_t base = (size_t)a * ZC + z;
    float mdr[8], mdi[8], xdr[8], xdi[8], im[8], ix[8];
    load8d(den + 0 * PS + base, mdr);
    load8d(den + 1 * PS + base, mdi);
    load8d(den + 2 * PS + base, xdr);
    load8d(den + 3 * PS + base, xdi);
#pragma unroll
    for (int e = 0; e < 8; ++e) {
      im[e] = 1.f / (mdr[e] * mdr[e] + mdi[e] * mdi[e]);
      ix[e] = 1.f / (xdr[e] * xdr[e] + xdi[e] * xdi[e]);
    }
#pragma unroll
    for (int d = 0; d < 8; ++d) {
      float ar[8], ai[8], br[8], bi[8];
      load8f(C + (size_t)(2 * d) * PS + base, ar);
      load8f(C + (size_t)(2 * d + 1) * PS + base, ai);
      load8f(C + (size_t)(16 + 2 * d) * PS + base, br);
      load8f(C + (size_t)(17 + 2 * d) * PS + base, bi);
#pragma unroll
      for (int e = 0; e < 8; ++e) {
        float r1 = (ar[e] * mdr[e] + ai[e] * mdi[e]) * im[e];
        float i1 = (ai[e] * mdr[e] - ar[e] * mdi[e]) * im[e];
        float r2 = (br[e] * xdr[e] + bi[e] * xdi[e]) * ix[e];
        float i2 = (bi[e] * xdr[e] - br[e] * xdi[e]) * ix[e];
        float dr = r1 - r2, di = i1 - i2;
        acc += dr * dr + di * di;
      }
    }
  }
  for (int off = 32; off; off >>= 1) acc += __shfl_down(acc, off, 64);
  __shared__ float red[4];
  if (!(tid & 63)) red[tid >> 6] = acc;
  __syncthreads();
  if (tid == 0) partials[slot * 1000 + a] = red[0] + red[1];
  if (tid == 128) partials[slot * 1000 + a] = red[2] + red[3];
}

__global__ __launch_bounds__(256) void k_final(const float* __restrict__ partials,
                                               float* __restrict__ out, int n) {
  int tid = threadIdx.x;
  float s = 0.f;
  for (int i = tid; i < n; i += 256) s += partials[i];
  for (int off = 32; off; off >>= 1) s += __shfl_down(s, off, 64);
  __shared__ float red[4];
  if (!(tid & 63)) red[tid >> 6] = s;
  __syncthreads();
  if (!tid) out[0] = (red[0] + red[1] + red[2] + red[3]) * (1.f / 2000000.f);
}

// ============================================================================
extern "C" void kernel_launch(void* const* d_in, const int* in_sizes, int n_in,
                              void* d_out, int out_size, void* d_ws,
                              size_t ws_size, hipStream_t stream) {
  const float* Mm  = (const float*)d_in[0];
  const float* Nm  = (const float*)d_in[1];
  const float* Xm  = (const float*)d_in[2];
  const float* ll  = (const float*)d_in[3];
  const float* K11 = (const float*)d_in[4];
  const float* K12 = (const float*)d_in[5];
  const float* gMN = (const float*)d_in[6];
  const float* gN  = (const float*)d_in[7];
  const float* al  = (const float*)d_in[8];

  char* ws = (char*)d_ws;
  const size_t MB = 1024 * 1024;
  bf16* AphH     = (bf16*)(ws);             // 16 MB
  bf16* AphL     = (bf16*)(ws + 16 * MB);   // 16 MB
  bf16* Kbf      = (bf16*)(ws + 32 * MB);   // 8 MB
  bf16* K12T     = (bf16*)(ws + 40 * MB);   // 8 MB
  float* partials= (float*)(ws + 48 * MB);  // <=64 KB
  char* chunkRgn = ws + 49 * MB;

  // chunk: Bt 20 planes (81920*ZC) | den fp32 (16384*ZC) | Cout bf16 (65536*ZC)
  size_t avail = (ws_size > 49 * MB) ? ws_size - 49 * MB : 0;
  int ZC = 2048;
  while (ZC > 128 && (size_t)163840 * ZC > avail) ZC >>= 1;
  int NC = 2048 / ZC;
  bf16* Btc   = (bf16*)(chunkRgn);
  float* denc = (float*)(chunkRgn + (size_t)81920 * ZC);
  bf16* Coutc = (bf16*)(chunkRgn + (size_t)98304 * ZC);

  k_phases<<<dim3(1024, 8), dim3(256), 0, stream>>>(al, Nm, Xm, AphH, AphL);
  k_cvt_straight<<<dim3(2048), dim3(256), 0, stream>>>(K11, Kbf);
  k_cvt_t<<<dim3(32, 32), dim3(256), 0, stream>>>(K12, K12T);
  for (int c = 0; c < NC; ++c) {
    int zg0 = c * ZC;
    int NB1 = 16 * (ZC / 128);             // gemm1 blocks
    int NB2 = 32 * (ZC / 64);              // buildB blocks
    k_prep<<<dim3(NB1 + NB2), dim3(256), 0, stream>>>(
        K12T, Kbf, K12, Xm, ll, gN, gMN, Mm, Btc, zg0, ZC, NB1);
    gemm2_kernel<<<dim3(8, ZC / 128, 16), dim3(256), 0, stream>>>(AphH, Btc,
                                                                  Coutc, ZC);
    k_den<<<dim3(8, ZC / 64, 4), dim3(256), 0, stream>>>(AphH, AphL, Btc,
                                                         denc, ZC);
    k_reduce<<<dim3(500), dim3(256), 0, stream>>>(Coutc, denc, partials, ZC,
                                                  zg0, c);
  }
  k_final<<<dim3(1), dim3(256), 0, stream>>>(partials, (float*)d_out,
                                             NC * 1000);
  (void)in_sizes; (void)n_in; (void)out_size;
}

// Round 5
// 682.748 us; speedup vs baseline: 1.2357x; 1.0250x over previous
//
#include <hip/hip_runtime.h>

// ============================================================================
// XModel_66795331387584: complex phase-feature ridge loss on MI355X (gfx950)
//
// loss = mean_{a,z} sum_d | num_MN/den_MN - num_X/den_X |^2
// den path: split-bf16 (hi+lo), fp32 out (tail-dominated 1/|den|^2).
// gamma_X via 1-term Neumann: gx = (K12 - K@K12/reg)/reg (rel err 4e-6).
//
// R5: one k_mm dispatch per chunk (blockIdx.z: 0-15 num planes 128x128 with
// 2 C-planes; 16-23 den tiles 128x64 split-bf16 3-MFMA chain) — tail-filling.
// k_prep branch-A epilogue now stages C through LDS and stores coalesced
// bf16x8 (was 640 scalar 2B stores/thread).
// ============================================================================

typedef __bf16 bf16;
typedef __bf16 bf16x8 __attribute__((ext_vector_type(8)));
typedef float f32x4 __attribute__((ext_vector_type(4)));

#define AS1 __attribute__((address_space(1)))
#define AS3 __attribute__((address_space(3)))

__device__ __forceinline__ void async16(const void* g, void* l) {
  __builtin_amdgcn_global_load_lds((AS1 const unsigned int*)g,
                                   (AS3 unsigned int*)l, 16, 0, 0);
}

// ------------------------------- phases (hi/lo) -----------------------------
__global__ __launch_bounds__(256) void k_phases(
    const float* __restrict__ al, const float* __restrict__ Nm,
    const float* __restrict__ Xm, bf16* __restrict__ AphH,
    bf16* __restrict__ AphL) {
  const size_t PA = (size_t)1024 * 2048;
  int a = blockIdx.x;
  int j = blockIdx.y * 256 + threadIdx.x;
  size_t o = (size_t)a * 2048 + j;
  float v[4] = {0.f, 0.f, 0.f, 0.f};
  if (a < 1000 && j < 2000) {
    const float4* N4 = (const float4*)Nm;
    const float4* X4 = (const float4*)Xm;
    const float4* A4 = (const float4*)al;
    float4 n0 = N4[j * 2], n1 = N4[j * 2 + 1];
    float4 x0 = X4[j * 2], x1 = X4[j * 2 + 1];
    float4 a0 = A4[a * 2], a1 = A4[a * 2 + 1];
    float pn = a0.x * n0.x + a0.y * n0.y + a0.z * n0.z + a0.w * n0.w +
               a1.x * n1.x + a1.y * n1.y + a1.z * n1.z + a1.w * n1.w;
    float px = a0.x * x0.x + a0.y * x0.y + a0.z * x0.z + a0.w * x0.w +
               a1.x * x1.x + a1.y * x1.y + a1.z * x1.z + a1.w * x1.w;
    sincosf(pn, &v[1], &v[0]);
    sincosf(px, &v[3], &v[2]);
  }
#pragma unroll
  for (int p = 0; p < 4; ++p) {
    bf16 h = (bf16)v[p];
    AphH[p * PA + o] = h;
    AphL[p * PA + o] = (bf16)(v[p] - (float)h);
  }
}

// --------------------------- converts --------------------------------------
__global__ __launch_bounds__(256) void k_cvt_straight(
    const float* __restrict__ K, bf16* __restrict__ Kb) {
  int e = (blockIdx.x * 256 + threadIdx.x) * 8;
  int j = e >> 11, k = e & 2047;
  bf16x8 v;
  if (j < 2000 && k < 2000) {
    const float4* s = (const float4*)(K + (size_t)j * 2000 + k);
    float4 f0 = s[0], f1 = s[1];
    v[0] = (bf16)f0.x; v[1] = (bf16)f0.y; v[2] = (bf16)f0.z; v[3] = (bf16)f0.w;
    v[4] = (bf16)f1.x; v[5] = (bf16)f1.y; v[6] = (bf16)f1.z; v[7] = (bf16)f1.w;
  } else {
    for (int i = 0; i < 8; ++i) v[i] = (bf16)0.f;
  }
  *(bf16x8*)(Kb + e) = v;
}

__global__ __launch_bounds__(256) void k_cvt_t(
    const float* __restrict__ src, bf16* __restrict__ dst) {
  int j0 = blockIdx.x * 64, z0 = blockIdx.y * 64;
  __shared__ float t[64][65];
  int tid = threadIdx.x;
  for (int e = tid; e < 4096; e += 256) {
    int r = e >> 6, c = e & 63;
    t[r][c] = (j0 + r < 2000 && z0 + c < 2000)
                  ? src[(size_t)(j0 + r) * 2000 + z0 + c] : 0.f;
  }
  __syncthreads();
  for (int e = tid; e < 4096; e += 256) {
    int r = e >> 6, c = e & 63;
    dst[(size_t)(z0 + r) * 2048 + j0 + c] = (bf16)t[c][r];
  }
}

// --------------------- unified num+den GEMM dispatch ------------------------
// z in [0,16): num plane bp=z, 128x128 tile, C planes 2bp (cos), 2bp+1 (sin)
// z in [16,24): den tiles 128x64, split-bf16 3-chain, fp32 out
__global__ __launch_bounds__(256, 2) void k_mm(
    const bf16* __restrict__ AphH, const bf16* __restrict__ AphL,
    const bf16* __restrict__ Bt, bf16* __restrict__ Cout,
    float* __restrict__ den, int ZC) {
  const size_t PA = (size_t)1024 * 2048;
  const size_t PL = (size_t)ZC * 2048;
  const size_t PC = (size_t)1024 * ZC;
  __shared__ __align__(16) bf16 smem[3 * 128 * 64];  // 48 KB
  const int tid = threadIdx.x;
  const int w = tid >> 6, ln = tid & 63;
  const int fr = ln & 15, kq = (ln >> 4) * 8;
  const int cr = (ln >> 4) * 4, cc = ln & 15;
  const int zb = blockIdx.z;

  if (zb < 16) {
    // ---------------- num plane ----------------
    bf16(*lds)[128][64] = (bf16(*)[128][64])smem;
    const bf16* A0 = AphH + (size_t)(zb < 8 ? 0 : 2) * PA;
    const bf16* A1 = A0 + PA;
    const bf16* B = Bt + (size_t)(4 + zb) * PL;
    bf16* C0 = Cout + (size_t)(2 * zb) * PC;
    bf16* C1 = C0 + PC;
    int bm = blockIdx.x * 128, bn = blockIdx.y * 128;
    const int r8 = ln >> 3, c8 = (ln & 7) * 8;

    f32x4 acc0[4][4], acc1[4][4];
#pragma unroll
    for (int i = 0; i < 4; i++)
#pragma unroll
      for (int j = 0; j < 4; j++) {
        acc0[i][j] = {0.f, 0.f, 0.f, 0.f};
        acc1[i][j] = {0.f, 0.f, 0.f, 0.f};
      }
    const int m0 = (w & 1) * 64, n0 = (w >> 1) * 64;

    for (int kt = 0; kt < 2048; kt += 64) {
#pragma unroll
      for (int q = 0; q < 4; ++q) {
        int row = (w * 4 + q) * 8 + r8;
        async16(A0 + (size_t)(bm + row) * 2048 + (kt + c8), &lds[0][row][c8]);
        async16(A1 + (size_t)(bm + row) * 2048 + (kt + c8), &lds[1][row][c8]);
        async16(B + (size_t)(bn + row) * 2048 + (kt + c8), &lds[2][row][c8]);
      }
      __syncthreads();
#pragma unroll
      for (int ks = 0; ks < 64; ks += 32) {
        bf16x8 a0[4], a1[4], b[4];
#pragma unroll
        for (int i = 0; i < 4; i++) {
          a0[i] = *(const bf16x8*)&lds[0][m0 + i * 16 + fr][ks + kq];
          a1[i] = *(const bf16x8*)&lds[1][m0 + i * 16 + fr][ks + kq];
          b[i] = *(const bf16x8*)&lds[2][n0 + i * 16 + fr][ks + kq];
        }
#pragma unroll
        for (int i = 0; i < 4; i++)
#pragma unroll
          for (int j = 0; j < 4; j++) {
            acc0[i][j] = __builtin_amdgcn_mfma_f32_16x16x32_bf16(
                a0[i], b[j], acc0[i][j], 0, 0, 0);
            acc1[i][j] = __builtin_amdgcn_mfma_f32_16x16x32_bf16(
                a1[i], b[j], acc1[i][j], 0, 0, 0);
          }
      }
      __syncthreads();
    }
#pragma unroll
    for (int i = 0; i < 4; i++)
#pragma unroll
      for (int j = 0; j < 4; j++)
#pragma unroll
        for (int r = 0; r < 4; r++) {
          size_t idx = (size_t)(bm + m0 + i * 16 + cr + r) * ZC +
                       (bn + n0 + j * 16 + cc);
          C0[idx] = (bf16)acc0[i][j][r];
          C1[idx] = (bf16)acc1[i][j][r];
        }
  } else {
    // ---------------- den tile (split-bf16, 128x64) ----------------
    bf16(*lds)[64] = (bf16(*)[64])smem;  // rows: Ah[0,128) Al[128,256)
                                         //       Bh[256,320) Bl[320,384)
    int nyTiles = ZC / 64;
    int den_idx = (zb - 16) * (ZC / 128) + blockIdx.y;  // [0, ZC/16)
    int p = den_idx / nyTiles;                          // 0..3
    int ny = den_idx % nyTiles;
    int side = p >> 1, trig = p & 1;
    const bf16* Ah = AphH + (size_t)(side * 2 + trig) * PA;
    const bf16* Al = AphL + (size_t)(side * 2 + trig) * PA;
    const bf16* Bh = Bt + (size_t)(side * 2) * PL;
    const bf16* Bl = Bh + PL;
    float* C = den + (size_t)p * PC;
    int bm = blockIdx.x * 128, bn = ny * 64;
    const int r32 = tid >> 3, c8 = (tid & 7) * 8;

    f32x4 acc[4][2];
#pragma unroll
    for (int i = 0; i < 4; i++)
#pragma unroll
      for (int j = 0; j < 2; j++) acc[i][j] = {0.f, 0.f, 0.f, 0.f};
    const int m0 = (w & 1) * 64, n0 = (w >> 1) * 32;

    for (int kt = 0; kt < 2048; kt += 64) {
#pragma unroll
      for (int q = 0; q < 4; ++q) {
        int row = q * 32 + r32;
        async16(Ah + (size_t)(bm + row) * 2048 + (kt + c8), &lds[row][c8]);
        async16(Al + (size_t)(bm + row) * 2048 + (kt + c8),
                &lds[128 + row][c8]);
      }
#pragma unroll
      for (int q = 0; q < 2; ++q) {
        int row = q * 32 + r32;
        async16(Bh + (size_t)(bn + row) * 2048 + (kt + c8),
                &lds[256 + row][c8]);
        async16(Bl + (size_t)(bn + row) * 2048 + (kt + c8),
                &lds[320 + row][c8]);
      }
      __syncthreads();
#pragma unroll
      for (int ks = 0; ks < 64; ks += 32) {
        bf16x8 ah[4], alo[4], bh[2], blo[2];
#pragma unroll
        for (int i = 0; i < 4; i++) {
          ah[i]  = *(const bf16x8*)&lds[m0 + i * 16 + fr][ks + kq];
          alo[i] = *(const bf16x8*)&lds[128 + m0 + i * 16 + fr][ks + kq];
        }
#pragma unroll
        for (int j = 0; j < 2; j++) {
          bh[j]  = *(const bf16x8*)&lds[256 + n0 + j * 16 + fr][ks + kq];
          blo[j] = *(const bf16x8*)&lds[320 + n0 + j * 16 + fr][ks + kq];
        }
#pragma unroll
        for (int i = 0; i < 4; i++)
#pragma unroll
          for (int j = 0; j < 2; j++) {
            acc[i][j] = __builtin_amdgcn_mfma_f32_16x16x32_bf16(
                alo[i], bh[j], acc[i][j], 0, 0, 0);
            acc[i][j] = __builtin_amdgcn_mfma_f32_16x16x32_bf16(
                ah[i], blo[j], acc[i][j], 0, 0, 0);
            acc[i][j] = __builtin_amdgcn_mfma_f32_16x16x32_bf16(
                ah[i], bh[j], acc[i][j], 0, 0, 0);
          }
      }
      __syncthreads();
    }
#pragma unroll
    for (int i = 0; i < 4; i++)
#pragma unroll
      for (int j = 0; j < 2; j++)
#pragma unroll
        for (int r = 0; r < 4; r++) {
          size_t idx = (size_t)(bm + m0 + i * 16 + cr + r) * ZC +
                       (bn + n0 + j * 16 + cc);
          C[idx] = acc[i][j][r];
        }
  }
}

// ------------- k_prep: gemm1+gammaX epilogue (A) + buildB (B) ---------------
__global__ __launch_bounds__(256, 2) void k_prep(
    const bf16* __restrict__ K12T, const bf16* __restrict__ Kbf,
    const float* __restrict__ K12, const float* __restrict__ Xm,
    const float* __restrict__ ll, const float* __restrict__ gN,
    const float* __restrict__ gMN, const float* __restrict__ Mm,
    bf16* __restrict__ Bt, int zg0, int ZC, int NB1) {
  const size_t PL = (size_t)ZC * 2048;
  __shared__ __align__(16) char smem[34816];
  const int tid = threadIdx.x;

  if ((int)blockIdx.x < NB1) {
    // ---- branch A: T1[z][j] = K12T[zg0+z][:] . Kbf[j][:]; gx epilogue
    bf16(*lds)[128][64] = (bf16(*)[128][64])smem;  // 32 KB
    int bm = ((int)blockIdx.x >> 4) * 128;  // z-tile (chunk-local)
    int bn = ((int)blockIdx.x & 15) * 128;  // j-tile
    const bf16* A0 = K12T + (size_t)zg0 * 2048;
    const int w = tid >> 6, ln = tid & 63;
    const int r8 = ln >> 3, c8 = (ln & 7) * 8;
    f32x4 acc[4][4];
#pragma unroll
    for (int i = 0; i < 4; i++)
#pragma unroll
      for (int j = 0; j < 4; j++) acc[i][j] = {0.f, 0.f, 0.f, 0.f};
    const int m0 = (w & 1) * 64, n0 = (w >> 1) * 64;
    const int fr = ln & 15, kq = (ln >> 4) * 8;
    for (int kt = 0; kt < 2048; kt += 64) {
#pragma unroll
      for (int q = 0; q < 4; ++q) {
        int row = (w * 4 + q) * 8 + r8;
        async16(A0 + (size_t)(bm + row) * 2048 + (kt + c8), &lds[0][row][c8]);
        async16(Kbf + (size_t)(bn + row) * 2048 + (kt + c8), &lds[1][row][c8]);
      }
      __syncthreads();
#pragma unroll
      for (int ks = 0; ks < 64; ks += 32) {
        bf16x8 a[4], b[4];
#pragma unroll
        for (int i = 0; i < 4; i++) {
          a[i] = *(const bf16x8*)&lds[0][m0 + i * 16 + fr][ks + kq];
          b[i] = *(const bf16x8*)&lds[1][n0 + i * 16 + fr][ks + kq];
        }
#pragma unroll
        for (int i = 0; i < 4; i++)
#pragma unroll
          for (int j = 0; j < 4; j++)
            acc[i][j] = __builtin_amdgcn_mfma_f32_16x16x32_bf16(
                a[i], b[j], acc[i][j], 0, 0, 0);
      }
      __syncthreads();
    }
    // epilogue: stage per n-half through LDS, store coalesced bf16x8
    float inv = 1.f / (2000.f * __expf(ll[0]));
    float* ft = (float*)smem;  // [128][68] = 34816 B
    const int cr = (ln >> 4) * 4, cc = ln & 15;
    const float4* X4 = (const float4*)Xm;
    const int gtid = (tid & 7) * 8;  // j-group base (fixed per thread)
#pragma unroll
    for (int h = 0; h < 2; ++h) {
      if ((w >> 1) == h) {
#pragma unroll
        for (int i = 0; i < 4; i++)
#pragma unroll
          for (int j = 0; j < 4; j++)
#pragma unroll
            for (int r = 0; r < 4; r++)
              ft[(m0 + i * 16 + cr + r) * 68 + j * 16 + cc] = acc[i][j][r];
      }
      __syncthreads();
      // X values for this thread's 8 j's
      float xv[8][8];
      int jbase = bn + h * 64 + gtid;
#pragma unroll
      for (int e = 0; e < 8; ++e) {
        int jj = jbase + e;
        if (jj < 2000) {
          float4 xa = X4[jj * 2], xb = X4[jj * 2 + 1];
          xv[e][0] = xa.x; xv[e][1] = xa.y; xv[e][2] = xa.z; xv[e][3] = xa.w;
          xv[e][4] = xb.x; xv[e][5] = xb.y; xv[e][6] = xb.z; xv[e][7] = xb.w;
        } else {
#pragma unroll
          for (int d = 0; d < 8; ++d) xv[e][d] = 0.f;
        }
      }
#pragma unroll
      for (int it = 0; it < 4; ++it) {
        int idx = it * 256 + tid;
        int m = idx >> 3;  // z-local row
        int zz = bm + m, zg = zg0 + zz;
        bool zok = zg < 2000;
        float gx[8];
#pragma unroll
        for (int e = 0; e < 8; ++e) {
          int jj = jbase + e;
          float t1 = ft[m * 68 + gtid + e];
          float k12 =
              (zok && jj < 2000) ? K12[(size_t)jj * 2000 + zg] : 0.f;
          gx[e] = (jj < 2000) ? (k12 - t1 * inv) * inv : 0.f;
        }
        size_t ob = (size_t)zz * 2048 + jbase;
        bf16x8 vh, vl;
#pragma unroll
        for (int e = 0; e < 8; ++e) {
          bf16 hh = (bf16)gx[e];
          vh[e] = hh;
          vl[e] = (bf16)(gx[e] - (float)hh);
        }
        *(bf16x8*)(Bt + 2 * PL + ob) = vh;
        *(bf16x8*)(Bt + 3 * PL + ob) = vl;
#pragma unroll
        for (int d = 0; d < 8; ++d) {
          bf16x8 v;
#pragma unroll
          for (int e = 0; e < 8; ++e) v[e] = (bf16)(gx[e] * xv[e][d]);
          *(bf16x8*)(Bt + (size_t)(12 + d) * PL + ob) = v;
        }
      }
      __syncthreads();
    }
  } else {
    // ---- branch B: gN hi/lo (planes 0,1), M_d*gMN (planes 4..11)
    float(*t)[65] = (float(*)[65])smem;
    int bid = (int)blockIdx.x - NB1;
    int j0 = (bid & 31) * 64;
    int zl0 = (bid >> 5) * 64;
    int zg = zg0 + zl0;

    for (int e = tid; e < 4096; e += 256) {
      int r = e >> 6, c = e & 63;
      t[r][c] = (j0 + r < 2000 && zg + c < 2000)
                    ? gN[(size_t)(j0 + r) * 2000 + zg + c] : 0.f;
    }
    __syncthreads();
#pragma unroll
    for (int it = 0; it < 2; ++it) {
      int idx = it * 256 + tid;
      int zr = idx >> 3, c8 = (idx & 7) * 8;
      bf16x8 vh, vl;
#pragma unroll
      for (int e = 0; e < 8; ++e) {
        float g = t[c8 + e][zr];
        bf16 h = (bf16)g;
        vh[e] = h;
        vl[e] = (bf16)(g - (float)h);
      }
      size_t ob = (size_t)(zl0 + zr) * 2048 + j0 + c8;
      *(bf16x8*)(Bt + 0 * PL + ob) = vh;
      *(bf16x8*)(Bt + 1 * PL + ob) = vl;
    }
    __syncthreads();

    for (int e = tid; e < 4096; e += 256) {
      int r = e >> 6, c = e & 63;
      t[r][c] = (j0 + r < 2000 && zg + c < 2000)
                    ? gMN[(size_t)(j0 + r) * 2000 + zg + c] : 0.f;
    }
    __syncthreads();
    const float4* M4 = (const float4*)Mm;
#pragma unroll
    for (int it = 0; it < 2; ++it) {
      int idx = it * 256 + tid;
      int zr = idx >> 3, c8 = (idx & 7) * 8;
      float g[8], mrow[8][8];
#pragma unroll
      for (int e = 0; e < 8; ++e) {
        g[e] = t[c8 + e][zr];
        int jj = j0 + c8 + e;
        if (jj < 2000) {
          float4 ma = M4[jj * 2], mb = M4[jj * 2 + 1];
          mrow[e][0] = ma.x; mrow[e][1] = ma.y; mrow[e][2] = ma.z;
          mrow[e][3] = ma.w; mrow[e][4] = mb.x; mrow[e][5] = mb.y;
          mrow[e][6] = mb.z; mrow[e][7] = mb.w;
        } else {
#pragma unroll
          for (int d = 0; d < 8; ++d) mrow[e][d] = 0.f;
        }
      }
      size_t ob = (size_t)(zl0 + zr) * 2048 + j0 + c8;
#pragma unroll
      for (int d = 0; d < 8; ++d) {
        bf16x8 v;
#pragma unroll
        for (int e = 0; e < 8; ++e) v[e] = (bf16)(g[e] * mrow[e][d]);
        *(bf16x8*)(Bt + (size_t)(4 + d) * PL + ob) = v;
      }
    }
  }
}

// --------------------------- final reduction -------------------------------
__device__ __forceinline__ void load8f(const bf16* p, float* o) {
  uint4 u = *(const uint4*)p;
  o[0] = __uint_as_float(u.x << 16);
  o[1] = __uint_as_float(u.x & 0xffff0000u);
  o[2] = __uint_as_float(u.y << 16);
  o[3] = __uint_as_float(u.y & 0xffff0000u);
  o[4] = __uint_as_float(u.z << 16);
  o[5] = __uint_as_float(u.z & 0xffff0000u);
  o[6] = __uint_as_float(u.w << 16);
  o[7] = __uint_as_float(u.w & 0xffff0000u);
}
__device__ __forceinline__ void load8d(const float* p, float* o) {
  float4 f0 = ((const float4*)p)[0], f1 = ((const float4*)p)[1];
  o[0] = f0.x; o[1] = f0.y; o[2] = f0.z; o[3] = f0.w;
  o[4] = f1.x; o[5] = f1.y; o[6] = f1.z; o[7] = f1.w;
}

__global__ __launch_bounds__(256) void k_reduce(
    const bf16* __restrict__ C, const float* __restrict__ den,
    float* __restrict__ partials, int ZC, int zg0, int slot) {
  const size_t PS = (size_t)1024 * ZC;
  int tid = threadIdx.x;
  int a = blockIdx.x * 2 + (tid >> 7);
  int zt = tid & 127;
  float acc = 0.f;
  for (int z = zt * 8; z < ZC; z += 1024) {
    if (zg0 + z >= 2000) break;
    size_t base = (size_t)a * ZC + z;
    float mdr[8], mdi[8], xdr[8], xdi[8], im[8], ix[8];
    load8d(den + 0 * PS + base, mdr);
    load8d(den + 1 * PS + base, mdi);
    load8d(den + 2 * PS + base, xdr);
    load8d(den + 3 * PS + base, xdi);
#pragma unroll
    for (int e = 0; e < 8; ++e) {
      im[e] = 1.f / (mdr[e] * mdr[e] + mdi[e] * mdi[e]);
      ix[e] = 1.f / (xdr[e] * xdr[e] + xdi[e] * xdi[e]);
    }
#pragma unroll
    for (int d = 0; d < 8; ++d) {
      float ar[8], ai[8], br[8], bi[8];
      load8f(C + (size_t)(2 * d) * PS + base, ar);
      load8f(C + (size_t)(2 * d + 1) * PS + base, ai);
      load8f(C + (size_t)(16 + 2 * d) * PS + base, br);
      load8f(C + (size_t)(17 + 2 * d) * PS + base, bi);
#pragma unroll
      for (int e = 0; e < 8; ++e) {
        float r1 = (ar[e] * mdr[e] + ai[e] * mdi[e]) * im[e];
        float i1 = (ai[e] * mdr[e] - ar[e] * mdi[e]) * im[e];
        float r2 = (br[e] * xdr[e] + bi[e] * xdi[e]) * ix[e];
        float i2 = (bi[e] * xdr[e] - br[e] * xdi[e]) * ix[e];
        float dr = r1 - r2, di = i1 - i2;
        acc += dr * dr + di * di;
      }
    }
  }
  for (int off = 32; off; off >>= 1) acc += __shfl_down(acc, off, 64);
  __shared__ float red[4];
  if (!(tid & 63)) red[tid >> 6] = acc;
  __syncthreads();
  if (tid == 0) partials[slot * 1000 + a] = red[0] + red[1];
  if (tid == 128) partials[slot * 1000 + a] = red[2] + red[3];
}

__global__ __launch_bounds__(256) void k_final(const float* __restrict__ partials,
                                               float* __restrict__ out, int n) {
  int tid = threadIdx.x;
  float s = 0.f;
  for (int i = tid; i < n; i += 256) s += partials[i];
  for (int off = 32; off; off >>= 1) s += __shfl_down(s, off, 64);
  __shared__ float red[4];
  if (!(tid & 63)) red[tid >> 6] = s;
  __syncthreads();
  if (!tid) out[0] = (red[0] + red[1] + red[2] + red[3]) * (1.f / 2000000.f);
}

// ============================================================================
extern "C" void kernel_launch(void* const* d_in, const int* in_sizes, int n_in,
                              void* d_out, int out_size, void* d_ws,
                              size_t ws_size, hipStream_t stream) {
  const float* Mm  = (const float*)d_in[0];
  const float* Nm  = (const float*)d_in[1];
  const float* Xm  = (const float*)d_in[2];
  const float* ll  = (const float*)d_in[3];
  const float* K11 = (const float*)d_in[4];
  const float* K12 = (const float*)d_in[5];
  const float* gMN = (const float*)d_in[6];
  const float* gN  = (const float*)d_in[7];
  const float* al  = (const float*)d_in[8];

  char* ws = (char*)d_ws;
  const size_t MB = 1024 * 1024;
  bf16* AphH     = (bf16*)(ws);             // 16 MB
  bf16* AphL     = (bf16*)(ws + 16 * MB);   // 16 MB
  bf16* Kbf      = (bf16*)(ws + 32 * MB);   // 8 MB
  bf16* K12T     = (bf16*)(ws + 40 * MB);   // 8 MB
  float* partials= (float*)(ws + 48 * MB);  // <=64 KB
  char* chunkRgn = ws + 49 * MB;

  // chunk: Bt 20 planes (81920*ZC) | den fp32 (16384*ZC) | Cout bf16 (65536*ZC)
  size_t avail = (ws_size > 49 * MB) ? ws_size - 49 * MB : 0;
  int ZC = 2048;
  while (ZC > 128 && (size_t)163840 * ZC > avail) ZC >>= 1;
  int NC = 2048 / ZC;
  bf16* Btc   = (bf16*)(chunkRgn);
  float* denc = (float*)(chunkRgn + (size_t)81920 * ZC);
  bf16* Coutc = (bf16*)(chunkRgn + (size_t)98304 * ZC);

  k_phases<<<dim3(1024, 8), dim3(256), 0, stream>>>(al, Nm, Xm, AphH, AphL);
  k_cvt_straight<<<dim3(2048), dim3(256), 0, stream>>>(K11, Kbf);
  k_cvt_t<<<dim3(32, 32), dim3(256), 0, stream>>>(K12, K12T);
  for (int c = 0; c < NC; ++c) {
    int zg0 = c * ZC;
    int NB1 = 16 * (ZC / 128);
    int NB2 = 32 * (ZC / 64);
    k_prep<<<dim3(NB1 + NB2), dim3(256), 0, stream>>>(
        K12T, Kbf, K12, Xm, ll, gN, gMN, Mm, Btc, zg0, ZC, NB1);
    k_mm<<<dim3(8, ZC / 128, 24), dim3(256), 0, stream>>>(AphH, AphL, Btc,
                                                          Coutc, denc, ZC);
    k_reduce<<<dim3(500), dim3(256), 0, stream>>>(Coutc, denc, partials, ZC,
                                                  zg0, c);
  }
  k_final<<<dim3(1), dim3(256), 0, stream>>>(partials, (float*)d_out,
                                             NC * 1000);
  (void)in_sizes; (void)n_in; (void)out_size;
}

// Round 6
// 658.149 us; speedup vs baseline: 1.2819x; 1.0374x over previous
//
#include <hip/hip_runtime.h>

// ============================================================================
// XModel_66795331387584: complex phase-feature ridge loss on MI355X (gfx950)
//
// loss = mean_{a,z} sum_d | num_MN/den_MN - num_X/den_X |^2
// den path: split-bf16 (hi+lo), fp32 out (tail-dominated 1/|den|^2).
// gamma_X via 1-term Neumann: gx = (K12 - K@K12/reg)/reg (rel err 4e-6).
//
// R6 structure:
//   k_pre    : phases (__sincosf, hi/lo), K->bf16, K12^T->bf16, zero out[0]
//   k_gemm1  : full-z gamma_X hi/lo (once, 256 blocks, K12 fp32 leading term)
//   per chunk: k_prep (elementwise B-planes) -> k_mm (16 num pair-planes
//              packed re|im + 4 den split-bf16) -> k_reduce (atomicAdd out)
// ============================================================================

typedef __bf16 bf16;
typedef __bf16 bf16x8 __attribute__((ext_vector_type(8)));
typedef float f32x4 __attribute__((ext_vector_type(4)));

#define AS1 __attribute__((address_space(1)))
#define AS3 __attribute__((address_space(3)))

__device__ __forceinline__ void async16(const void* g, void* l) {
  __builtin_amdgcn_global_load_lds((AS1 const unsigned int*)g,
                                   (AS3 unsigned int*)l, 16, 0, 0);
}

// ------------------- k_pre: phases + converts + out zero --------------------
__global__ __launch_bounds__(256) void k_pre(
    const float* __restrict__ al, const float* __restrict__ Nm,
    const float* __restrict__ Xm, const float* __restrict__ K11,
    const float* __restrict__ K12, bf16* __restrict__ AphH,
    bf16* __restrict__ AphL, bf16* __restrict__ Kbf,
    bf16* __restrict__ K12T, float* __restrict__ out) {
  __shared__ float t[64][65];
  const int bid = blockIdx.x, tid = threadIdx.x;
  if (bid < 8192) {
    // phases: a = bid>>3, j = (bid&7)*256+tid
    if (bid == 0 && tid == 0) out[0] = 0.f;
    const size_t PA = (size_t)1024 * 2048;
    int a = bid >> 3;
    int j = (bid & 7) * 256 + tid;
    size_t o = (size_t)a * 2048 + j;
    float v[4] = {0.f, 0.f, 0.f, 0.f};
    if (a < 1000 && j < 2000) {
      const float4* N4 = (const float4*)Nm;
      const float4* X4 = (const float4*)Xm;
      const float4* A4 = (const float4*)al;
      float4 n0 = N4[j * 2], n1 = N4[j * 2 + 1];
      float4 x0 = X4[j * 2], x1 = X4[j * 2 + 1];
      float4 a0 = A4[a * 2], a1 = A4[a * 2 + 1];
      float pn = a0.x * n0.x + a0.y * n0.y + a0.z * n0.z + a0.w * n0.w +
                 a1.x * n1.x + a1.y * n1.y + a1.z * n1.z + a1.w * n1.w;
      float px = a0.x * x0.x + a0.y * x0.y + a0.z * x0.z + a0.w * x0.w +
                 a1.x * x1.x + a1.y * x1.y + a1.z * x1.z + a1.w * x1.w;
      __sincosf(pn, &v[1], &v[0]);
      __sincosf(px, &v[3], &v[2]);
    }
#pragma unroll
    for (int p = 0; p < 4; ++p) {
      bf16 h = (bf16)v[p];
      AphH[p * PA + o] = h;
      AphL[p * PA + o] = (bf16)(v[p] - (float)h);
    }
  } else if (bid < 10240) {
    // K11 -> bf16 (straight, padded to 2048)
    int e = ((bid - 8192) * 256 + tid) * 8;
    int j = e >> 11, k = e & 2047;
    bf16x8 v;
    if (j < 2000 && k < 2000) {
      const float4* s = (const float4*)(K11 + (size_t)j * 2000 + k);
      float4 f0 = s[0], f1 = s[1];
      v[0] = (bf16)f0.x; v[1] = (bf16)f0.y; v[2] = (bf16)f0.z; v[3] = (bf16)f0.w;
      v[4] = (bf16)f1.x; v[5] = (bf16)f1.y; v[6] = (bf16)f1.z; v[7] = (bf16)f1.w;
    } else {
      for (int i = 0; i < 8; ++i) v[i] = (bf16)0.f;
    }
    *(bf16x8*)(Kbf + e) = v;
  } else {
    // K12^T -> bf16 (transpose, padded)
    int b2 = bid - 10240;
    int j0 = (b2 & 31) * 64, z0 = (b2 >> 5) * 64;
    for (int e = tid; e < 4096; e += 256) {
      int r = e >> 6, c = e & 63;
      t[r][c] = (j0 + r < 2000 && z0 + c < 2000)
                    ? K12[(size_t)(j0 + r) * 2000 + z0 + c] : 0.f;
    }
    __syncthreads();
    for (int e = tid; e < 4096; e += 256) {
      int r = e >> 6, c = e & 63;
      K12T[(size_t)(z0 + r) * 2048 + j0 + c] = (bf16)t[c][r];
    }
  }
}

// --------------- k_gemm1: full-z gamma_X hi/lo (Neumann fused) --------------
__global__ __launch_bounds__(256, 2) void k_gemm1(
    const bf16* __restrict__ K12T, const bf16* __restrict__ Kbf,
    const float* __restrict__ K12, const float* __restrict__ ll,
    bf16* __restrict__ gxHi, bf16* __restrict__ gxLo) {
  __shared__ __align__(16) char smem[34816];
  bf16(*lds)[128][64] = (bf16(*)[128][64])smem;
  const int tid = threadIdx.x;
  int bm = blockIdx.x * 128;  // z-tile (global)
  int bn = blockIdx.y * 128;  // j-tile
  const int w = tid >> 6, ln = tid & 63;
  const int r8 = ln >> 3, c8 = (ln & 7) * 8;
  f32x4 acc[4][4];
#pragma unroll
  for (int i = 0; i < 4; i++)
#pragma unroll
    for (int j = 0; j < 4; j++) acc[i][j] = {0.f, 0.f, 0.f, 0.f};
  const int m0 = (w & 1) * 64, n0 = (w >> 1) * 64;
  const int fr = ln & 15, kq = (ln >> 4) * 8;
  for (int kt = 0; kt < 2048; kt += 64) {
#pragma unroll
    for (int q = 0; q < 4; ++q) {
      int row = (w * 4 + q) * 8 + r8;
      async16(K12T + (size_t)(bm + row) * 2048 + (kt + c8), &lds[0][row][c8]);
      async16(Kbf + (size_t)(bn + row) * 2048 + (kt + c8), &lds[1][row][c8]);
    }
    __syncthreads();
#pragma unroll
    for (int ks = 0; ks < 64; ks += 32) {
      bf16x8 a[4], b[4];
#pragma unroll
      for (int i = 0; i < 4; i++) {
        a[i] = *(const bf16x8*)&lds[0][m0 + i * 16 + fr][ks + kq];
        b[i] = *(const bf16x8*)&lds[1][n0 + i * 16 + fr][ks + kq];
      }
#pragma unroll
      for (int i = 0; i < 4; i++)
#pragma unroll
        for (int j = 0; j < 4; j++)
          acc[i][j] = __builtin_amdgcn_mfma_f32_16x16x32_bf16(
              a[i], b[j], acc[i][j], 0, 0, 0);
    }
    __syncthreads();
  }
  // epilogue: stage fp32 T1 per n-half, gx = (K12 - T1*inv)*inv, hi/lo stores
  float inv = 1.f / (2000.f * __expf(ll[0]));
  float* ft = (float*)smem;  // [128][68]
  const int cr = (ln >> 4) * 4, cc = ln & 15;
  const int gtid = (tid & 7) * 8;
#pragma unroll
  for (int h = 0; h < 2; ++h) {
    if ((w >> 1) == h) {
#pragma unroll
      for (int i = 0; i < 4; i++)
#pragma unroll
        for (int j = 0; j < 4; j++)
#pragma unroll
          for (int r = 0; r < 4; r++)
            ft[(m0 + i * 16 + cr + r) * 68 + j * 16 + cc] = acc[i][j][r];
    }
    __syncthreads();
    int jbase = bn + h * 64 + gtid;
#pragma unroll
    for (int it = 0; it < 4; ++it) {
      int idx = it * 256 + tid;
      int m = idx >> 3;
      int zg = bm + m;
      bool zok = zg < 2000;
      float gx[8];
#pragma unroll
      for (int e = 0; e < 8; ++e) {
        int jj = jbase + e;
        float t1 = ft[m * 68 + gtid + e];
        float k12 = (zok && jj < 2000) ? K12[(size_t)jj * 2000 + zg] : 0.f;
        gx[e] = (jj < 2000) ? (k12 - t1 * inv) * inv : 0.f;
      }
      size_t ob = (size_t)zg * 2048 + jbase;
      bf16x8 vh, vl;
#pragma unroll
      for (int e = 0; e < 8; ++e) {
        bf16 hh = (bf16)gx[e];
        vh[e] = hh;
        vl[e] = (bf16)(gx[e] - (float)hh);
      }
      *(bf16x8*)(gxHi + ob) = vh;
      *(bf16x8*)(gxLo + ob) = vl;
    }
    __syncthreads();
  }
}

// ------------- k_prep: elementwise B-planes (per z-chunk) -------------------
// Bt planes [18][ZC][2048]: p0/p1 gN hi/lo; p2-9 M_d*gMN^T; p10-17 X_d*gX^T
__global__ __launch_bounds__(256) void k_prep(
    const float* __restrict__ gN, const float* __restrict__ gMN,
    const float* __restrict__ Mm, const float* __restrict__ Xm,
    const bf16* __restrict__ gxHi, const bf16* __restrict__ gxLo,
    bf16* __restrict__ Bt, int zg0, int ZC) {
  const size_t PL = (size_t)ZC * 2048;
  int j0 = blockIdx.x * 64, zl0 = blockIdx.y * 64;
  int zg = zg0 + zl0;
  int tid = threadIdx.x;
  __shared__ float t[64][65];

  // p0/p1: gammaN^T hi/lo (transpose)
  for (int e = tid; e < 4096; e += 256) {
    int r = e >> 6, c = e & 63;
    t[r][c] = (j0 + r < 2000 && zg + c < 2000)
                  ? gN[(size_t)(j0 + r) * 2000 + zg + c] : 0.f;
  }
  __syncthreads();
#pragma unroll
  for (int it = 0; it < 2; ++it) {
    int idx = it * 256 + tid;
    int zr = idx >> 3, c8 = (idx & 7) * 8;
    bf16x8 vh, vl;
#pragma unroll
    for (int e = 0; e < 8; ++e) {
      float g = t[c8 + e][zr];
      bf16 h = (bf16)g;
      vh[e] = h;
      vl[e] = (bf16)(g - (float)h);
    }
    size_t ob = (size_t)(zl0 + zr) * 2048 + j0 + c8;
    *(bf16x8*)(Bt + 0 * PL + ob) = vh;
    *(bf16x8*)(Bt + 1 * PL + ob) = vl;
  }
  __syncthreads();

  // p2..9: M_d * gammaMN^T (transpose)
  for (int e = tid; e < 4096; e += 256) {
    int r = e >> 6, c = e & 63;
    t[r][c] = (j0 + r < 2000 && zg + c < 2000)
                  ? gMN[(size_t)(j0 + r) * 2000 + zg + c] : 0.f;
  }
  __syncthreads();
  const float4* M4 = (const float4*)Mm;
  const float4* X4 = (const float4*)Xm;
#pragma unroll
  for (int it = 0; it < 2; ++it) {
    int idx = it * 256 + tid;
    int zr = idx >> 3, c8 = (idx & 7) * 8;
    float g[8], mrow[8][8];
#pragma unroll
    for (int e = 0; e < 8; ++e) {
      g[e] = t[c8 + e][zr];
      int jj = j0 + c8 + e;
      if (jj < 2000) {
        float4 ma = M4[jj * 2], mb = M4[jj * 2 + 1];
        mrow[e][0] = ma.x; mrow[e][1] = ma.y; mrow[e][2] = ma.z;
        mrow[e][3] = ma.w; mrow[e][4] = mb.x; mrow[e][5] = mb.y;
        mrow[e][6] = mb.z; mrow[e][7] = mb.w;
      } else {
#pragma unroll
        for (int d = 0; d < 8; ++d) mrow[e][d] = 0.f;
      }
    }
    size_t ob = (size_t)(zl0 + zr) * 2048 + j0 + c8;
#pragma unroll
    for (int d = 0; d < 8; ++d) {
      bf16x8 v;
#pragma unroll
      for (int e = 0; e < 8; ++e) v[e] = (bf16)(g[e] * mrow[e][d]);
      *(bf16x8*)(Bt + (size_t)(2 + d) * PL + ob) = v;
    }
  }

  // p10..17: X_d * gammaX^T (from gxFull, already [z][j])
#pragma unroll
  for (int it = 0; it < 2; ++it) {
    int idx = it * 256 + tid;
    int zr = idx >> 3, c8 = (idx & 7) * 8;
    size_t gb = (size_t)(zg + zr) * 2048 + j0 + c8;
    bf16x8 vh = *(const bf16x8*)(gxHi + gb);
    bf16x8 vl = *(const bf16x8*)(gxLo + gb);
    float gx[8], xr[8][8];
#pragma unroll
    for (int e = 0; e < 8; ++e) {
      gx[e] = (float)vh[e] + (float)vl[e];
      int jj = j0 + c8 + e;
      if (jj < 2000) {
        float4 xa = X4[jj * 2], xb = X4[jj * 2 + 1];
        xr[e][0] = xa.x; xr[e][1] = xa.y; xr[e][2] = xa.z; xr[e][3] = xa.w;
        xr[e][4] = xb.x; xr[e][5] = xb.y; xr[e][6] = xb.z; xr[e][7] = xb.w;
      } else {
#pragma unroll
        for (int d = 0; d < 8; ++d) xr[e][d] = 0.f;
      }
    }
    size_t ob = (size_t)(zl0 + zr) * 2048 + j0 + c8;
#pragma unroll
    for (int d = 0; d < 8; ++d) {
      bf16x8 v;
#pragma unroll
      for (int e = 0; e < 8; ++e) v[e] = (bf16)(gx[e] * xr[e][d]);
      *(bf16x8*)(Bt + (size_t)(10 + d) * PL + ob) = v;
    }
  }
}

// --------------------- unified num+den GEMM dispatch ------------------------
__global__ __launch_bounds__(256, 2) void k_mm(
    const bf16* __restrict__ AphH, const bf16* __restrict__ AphL,
    const bf16* __restrict__ Bt, const bf16* __restrict__ gxHi,
    const bf16* __restrict__ gxLo, unsigned int* __restrict__ Cpk,
    float* __restrict__ den, int ZC, int zg0) {
  const size_t PA = (size_t)1024 * 2048;
  const size_t PL = (size_t)ZC * 2048;
  const size_t PC = (size_t)1024 * ZC;  // uints per pair-plane / floats per den
  __shared__ __align__(16) bf16 smem[3 * 128 * 64];
  const int tid = threadIdx.x;
  const int w = tid >> 6, ln = tid & 63;
  const int fr = ln & 15, kq = (ln >> 4) * 8;
  const int cr = (ln >> 4) * 4, cc = ln & 15;
  const int zb = blockIdx.z;

  if (zb < 16) {
    // ---------------- num pair-plane (re,im packed) ----------------
    bf16(*lds)[128][64] = (bf16(*)[128][64])smem;
    const bf16* A0 = AphH + (size_t)(zb < 8 ? 0 : 2) * PA;
    const bf16* A1 = A0 + PA;
    const bf16* B = Bt + (size_t)(2 + zb) * PL;
    unsigned int* P = Cpk + (size_t)zb * PC;
    int bm = blockIdx.x * 128, bn = blockIdx.y * 128;
    const int r8 = ln >> 3, c8 = (ln & 7) * 8;

    f32x4 acc0[4][4], acc1[4][4];
#pragma unroll
    for (int i = 0; i < 4; i++)
#pragma unroll
      for (int j = 0; j < 4; j++) {
        acc0[i][j] = {0.f, 0.f, 0.f, 0.f};
        acc1[i][j] = {0.f, 0.f, 0.f, 0.f};
      }
    const int m0 = (w & 1) * 64, n0 = (w >> 1) * 64;

    for (int kt = 0; kt < 2048; kt += 64) {
#pragma unroll
      for (int q = 0; q < 4; ++q) {
        int row = (w * 4 + q) * 8 + r8;
        async16(A0 + (size_t)(bm + row) * 2048 + (kt + c8), &lds[0][row][c8]);
        async16(A1 + (size_t)(bm + row) * 2048 + (kt + c8), &lds[1][row][c8]);
        async16(B + (size_t)(bn + row) * 2048 + (kt + c8), &lds[2][row][c8]);
      }
      __syncthreads();
#pragma unroll
      for (int ks = 0; ks < 64; ks += 32) {
        bf16x8 a0[4], a1[4], b[4];
#pragma unroll
        for (int i = 0; i < 4; i++) {
          a0[i] = *(const bf16x8*)&lds[0][m0 + i * 16 + fr][ks + kq];
          a1[i] = *(const bf16x8*)&lds[1][m0 + i * 16 + fr][ks + kq];
          b[i] = *(const bf16x8*)&lds[2][n0 + i * 16 + fr][ks + kq];
        }
#pragma unroll
        for (int i = 0; i < 4; i++)
#pragma unroll
          for (int j = 0; j < 4; j++) {
            acc0[i][j] = __builtin_amdgcn_mfma_f32_16x16x32_bf16(
                a0[i], b[j], acc0[i][j], 0, 0, 0);
            acc1[i][j] = __builtin_amdgcn_mfma_f32_16x16x32_bf16(
                a1[i], b[j], acc1[i][j], 0, 0, 0);
          }
      }
      __syncthreads();
    }
#pragma unroll
    for (int i = 0; i < 4; i++)
#pragma unroll
      for (int j = 0; j < 4; j++)
#pragma unroll
        for (int r = 0; r < 4; r++) {
          union { bf16 h[2]; unsigned int u; } pk;
          pk.h[0] = (bf16)acc0[i][j][r];
          pk.h[1] = (bf16)acc1[i][j][r];
          P[(size_t)(bm + m0 + i * 16 + cr + r) * ZC +
            (bn + n0 + j * 16 + cc)] = pk.u;
        }
  } else {
    // ---------------- den tile (split-bf16, 128x64) ----------------
    bf16(*lds)[64] = (bf16(*)[64])smem;
    int nyTiles = ZC / 64;
    int den_idx = (zb - 16) * (ZC / 128) + blockIdx.y;
    int p = den_idx / nyTiles;  // 0 denN_re,1 denN_im,2 denX_re,3 denX_im
    int ny = den_idx % nyTiles;
    int side = p >> 1, trig = p & 1;
    const bf16* Ah = AphH + (size_t)(side * 2 + trig) * PA;
    const bf16* Al = AphL + (size_t)(side * 2 + trig) * PA;
    const bf16* Bh = side ? (gxHi + (size_t)zg0 * 2048) : (Bt + 0 * PL);
    const bf16* Bl = side ? (gxLo + (size_t)zg0 * 2048) : (Bt + 1 * PL);
    float* C = den + (size_t)p * PC;
    int bm = blockIdx.x * 128, bn = ny * 64;
    const int r32 = tid >> 3, c8 = (tid & 7) * 8;

    f32x4 acc[4][2];
#pragma unroll
    for (int i = 0; i < 4; i++)
#pragma unroll
      for (int j = 0; j < 2; j++) acc[i][j] = {0.f, 0.f, 0.f, 0.f};
    const int m0 = (w & 1) * 64, n0 = (w >> 1) * 32;

    for (int kt = 0; kt < 2048; kt += 64) {
#pragma unroll
      for (int q = 0; q < 4; ++q) {
        int row = q * 32 + r32;
        async16(Ah + (size_t)(bm + row) * 2048 + (kt + c8), &lds[row][c8]);
        async16(Al + (size_t)(bm + row) * 2048 + (kt + c8),
                &lds[128 + row][c8]);
      }
#pragma unroll
      for (int q = 0; q < 2; ++q) {
        int row = q * 32 + r32;
        async16(Bh + (size_t)(bn + row) * 2048 + (kt + c8),
                &lds[256 + row][c8]);
        async16(Bl + (size_t)(bn + row) * 2048 + (kt + c8),
                &lds[320 + row][c8]);
      }
      __syncthreads();
#pragma unroll
      for (int ks = 0; ks < 64; ks += 32) {
        bf16x8 ah[4], alo[4], bh[2], blo[2];
#pragma unroll
        for (int i = 0; i < 4; i++) {
          ah[i]  = *(const bf16x8*)&lds[m0 + i * 16 + fr][ks + kq];
          alo[i] = *(const bf16x8*)&lds[128 + m0 + i * 16 + fr][ks + kq];
        }
#pragma unroll
        for (int j = 0; j < 2; j++) {
          bh[j]  = *(const bf16x8*)&lds[256 + n0 + j * 16 + fr][ks + kq];
          blo[j] = *(const bf16x8*)&lds[320 + n0 + j * 16 + fr][ks + kq];
        }
#pragma unroll
        for (int i = 0; i < 4; i++)
#pragma unroll
          for (int j = 0; j < 2; j++) {
            acc[i][j] = __builtin_amdgcn_mfma_f32_16x16x32_bf16(
                alo[i], bh[j], acc[i][j], 0, 0, 0);
            acc[i][j] = __builtin_amdgcn_mfma_f32_16x16x32_bf16(
                ah[i], blo[j], acc[i][j], 0, 0, 0);
            acc[i][j] = __builtin_amdgcn_mfma_f32_16x16x32_bf16(
                ah[i], bh[j], acc[i][j], 0, 0, 0);
          }
      }
      __syncthreads();
    }
#pragma unroll
    for (int i = 0; i < 4; i++)
#pragma unroll
      for (int j = 0; j < 2; j++)
#pragma unroll
        for (int r = 0; r < 4; r++) {
          size_t idx = (size_t)(bm + m0 + i * 16 + cr + r) * ZC +
                       (bn + n0 + j * 16 + cc);
          C[idx] = acc[i][j][r];
        }
  }
}

// --------------------------- final reduction -------------------------------
__device__ __forceinline__ void load8p(const unsigned int* p, float* re,
                                       float* im) {
  uint4 u0 = ((const uint4*)p)[0], u1 = ((const uint4*)p)[1];
  re[0] = __uint_as_float(u0.x << 16); im[0] = __uint_as_float(u0.x & 0xffff0000u);
  re[1] = __uint_as_float(u0.y << 16); im[1] = __uint_as_float(u0.y & 0xffff0000u);
  re[2] = __uint_as_float(u0.z << 16); im[2] = __uint_as_float(u0.z & 0xffff0000u);
  re[3] = __uint_as_float(u0.w << 16); im[3] = __uint_as_float(u0.w & 0xffff0000u);
  re[4] = __uint_as_float(u1.x << 16); im[4] = __uint_as_float(u1.x & 0xffff0000u);
  re[5] = __uint_as_float(u1.y << 16); im[5] = __uint_as_float(u1.y & 0xffff0000u);
  re[6] = __uint_as_float(u1.z << 16); im[6] = __uint_as_float(u1.z & 0xffff0000u);
  re[7] = __uint_as_float(u1.w << 16); im[7] = __uint_as_float(u1.w & 0xffff0000u);
}
__device__ __forceinline__ void load8d(const float* p, float* o) {
  float4 f0 = ((const float4*)p)[0], f1 = ((const float4*)p)[1];
  o[0] = f0.x; o[1] = f0.y; o[2] = f0.z; o[3] = f0.w;
  o[4] = f1.x; o[5] = f1.y; o[6] = f1.z; o[7] = f1.w;
}

__global__ __launch_bounds__(256) void k_reduce(
    const unsigned int* __restrict__ Cpk, const float* __restrict__ den,
    float* __restrict__ out, int ZC, int zg0) {
  const size_t PS = (size_t)1024 * ZC;
  int tid = threadIdx.x;
  int a = blockIdx.x * 2 + (tid >> 7);
  int zt = tid & 127;
  float acc = 0.f;
  for (int z = zt * 8; z < ZC; z += 1024) {
    if (zg0 + z >= 2000) break;
    size_t base = (size_t)a * ZC + z;
    float mdr[8], mdi[8], xdr[8], xdi[8], im[8], ix[8];
    load8d(den + 0 * PS + base, mdr);
    load8d(den + 1 * PS + base, mdi);
    load8d(den + 2 * PS + base, xdr);
    load8d(den + 3 * PS + base, xdi);
#pragma unroll
    for (int e = 0; e < 8; ++e) {
      im[e] = 1.f / (mdr[e] * mdr[e] + mdi[e] * mdi[e]);
      ix[e] = 1.f / (xdr[e] * xdr[e] + xdi[e] * xdi[e]);
    }
#pragma unroll
    for (int d = 0; d < 8; ++d) {
      float ar[8], ai[8], br[8], bi[8];
      load8p(Cpk + (size_t)d * PS + base, ar, ai);
      load8p(Cpk + (size_t)(8 + d) * PS + base, br, bi);
#pragma unroll
      for (int e = 0; e < 8; ++e) {
        float r1 = (ar[e] * mdr[e] + ai[e] * mdi[e]) * im[e];
        float i1 = (ai[e] * mdr[e] - ar[e] * mdi[e]) * im[e];
        float r2 = (br[e] * xdr[e] + bi[e] * xdi[e]) * ix[e];
        float i2 = (bi[e] * xdr[e] - br[e] * xdi[e]) * ix[e];
        float dr = r1 - r2, di = i1 - i2;
        acc += dr * dr + di * di;
      }
    }
  }
  for (int off = 32; off; off >>= 1) acc += __shfl_down(acc, off, 64);
  __shared__ float red[4];
  if (!(tid & 63)) red[tid >> 6] = acc;
  __syncthreads();
  if (!tid)
    atomicAdd(out,
              (red[0] + red[1] + red[2] + red[3]) * (1.f / 2000000.f));
}

// ============================================================================
extern "C" void kernel_launch(void* const* d_in, const int* in_sizes, int n_in,
                              void* d_out, int out_size, void* d_ws,
                              size_t ws_size, hipStream_t stream) {
  const float* Mm  = (const float*)d_in[0];
  const float* Nm  = (const float*)d_in[1];
  const float* Xm  = (const float*)d_in[2];
  const float* ll  = (const float*)d_in[3];
  const float* K11 = (const float*)d_in[4];
  const float* K12 = (const float*)d_in[5];
  const float* gMN = (const float*)d_in[6];
  const float* gN  = (const float*)d_in[7];
  const float* al  = (const float*)d_in[8];

  char* ws = (char*)d_ws;
  const size_t MB = 1024 * 1024;
  bf16* AphH = (bf16*)(ws);             // 16 MB
  bf16* AphL = (bf16*)(ws + 16 * MB);   // 16 MB
  bf16* Kbf  = (bf16*)(ws + 32 * MB);   // 8 MB
  bf16* K12T = (bf16*)(ws + 40 * MB);   // 8 MB
  bf16* gxHi = (bf16*)(ws + 48 * MB);   // 8 MB [2048][2048]
  bf16* gxLo = (bf16*)(ws + 56 * MB);   // 8 MB
  char* chunkRgn = ws + 64 * MB;

  // chunk: Bt 18 planes (73728*ZC) | den fp32 (16384*ZC) | Cpk (65536*ZC)
  size_t avail = (ws_size > 64 * MB) ? ws_size - 64 * MB : 0;
  int ZC = 2048;
  while (ZC > 128 && (size_t)155648 * ZC > avail) ZC >>= 1;
  int NC = 2048 / ZC;
  bf16* Btc = (bf16*)(chunkRgn);
  float* denc = (float*)(chunkRgn + (size_t)73728 * ZC);
  unsigned int* Cpkc = (unsigned int*)(chunkRgn + (size_t)90112 * ZC);

  k_pre<<<dim3(11264), dim3(256), 0, stream>>>(al, Nm, Xm, K11, K12, AphH,
                                               AphL, Kbf, K12T,
                                               (float*)d_out);
  k_gemm1<<<dim3(16, 16), dim3(256), 0, stream>>>(K12T, Kbf, K12, ll, gxHi,
                                                  gxLo);
  for (int c = 0; c < NC; ++c) {
    int zg0 = c * ZC;
    k_prep<<<dim3(32, ZC / 64), dim3(256), 0, stream>>>(gN, gMN, Mm, Xm, gxHi,
                                                        gxLo, Btc, zg0, ZC);
    k_mm<<<dim3(8, ZC / 128, 24), dim3(256), 0, stream>>>(
        AphH, AphL, Btc, gxHi, gxLo, Cpkc, denc, ZC, zg0);
    k_reduce<<<dim3(500), dim3(256), 0, stream>>>(Cpkc, denc, (float*)d_out,
                                                  ZC, zg0);
  }
  (void)in_sizes; (void)n_in; (void)out_size;
}